// Round 9
// baseline (982.856 us; speedup 1.0000x reference)
//
#include <hip/hip_runtime.h>

#define DEV __device__ __forceinline__

constexpr int NN = 50000;   // nodes
constexpr int NE = 400000;  // edges
constexpr int NG = 32;      // graphs
constexpr float EPSV = 1e-5f;
constexpr int SCAN_BLOCKS = 196;  // 196*256 = 50176 >= NN

typedef __attribute__((ext_vector_type(8))) short s16x8;
typedef __attribute__((ext_vector_type(4))) float f32x4;

DEV unsigned short f2b(float f) {  // fp32 -> bf16 RNE (finite inputs)
  union { float f; unsigned u; } x; x.f = f;
  unsigned r = x.u + 0x7fffu + ((x.u >> 16) & 1u);
  return (unsigned short)(r >> 16);
}
DEV float b2f(unsigned short u) {
  union { unsigned u; float f; } x; x.u = ((unsigned)u) << 16; return x.f;
}

DEV s16x8 frag_from_f32(const float* p) {
  const float4 v0 = *(const float4*)p;
  const float4 v1 = *(const float4*)(p + 4);
  s16x8 af;
  af[0] = (short)f2b(v0.x); af[1] = (short)f2b(v0.y);
  af[2] = (short)f2b(v0.z); af[3] = (short)f2b(v0.w);
  af[4] = (short)f2b(v1.x); af[5] = (short)f2b(v1.y);
  af[6] = (short)f2b(v1.z); af[7] = (short)f2b(v1.w);
  return af;
}

// ---------------------------------------------------------------------------
// lin_in: h = x @ W(11x64) + b
// ---------------------------------------------------------------------------
__global__ __launch_bounds__(256) void lin_in_kernel(
    const float* __restrict__ x, const float* __restrict__ W,
    const float* __restrict__ b, float* __restrict__ h)
{
  int gid = blockIdx.x * 256 + threadIdx.x;
  if (gid >= NN * 64) return;
  int n = gid >> 6, c = gid & 63;
  float acc = b[c];
#pragma unroll
  for (int k = 0; k < 11; ++k)
    acc = fmaf(x[n * 11 + k], W[k * 64 + c], acc);
  h[gid] = acc;
}

// ---------------------------------------------------------------------------
// CSR build: histogram -> hierarchical exclusive scan -> permuting fill.
// ---------------------------------------------------------------------------
__global__ __launch_bounds__(256) void hist_kernel(
    const int* __restrict__ dstI, int* __restrict__ deg)
{
  int e = blockIdx.x * 256 + threadIdx.x;
  if (e < NE) atomicAdd(&deg[dstI[e]], 1);
}

__global__ __launch_bounds__(256) void scan_pass1(
    const int* __restrict__ deg, int* __restrict__ blockSums)
{
  __shared__ int red[4];
  int tid = threadIdx.x;
  int idx = blockIdx.x * 256 + tid;
  int v = (idx < NN) ? deg[idx] : 0;
#pragma unroll
  for (int off = 32; off > 0; off >>= 1) v += __shfl_down(v, off, 64);
  if ((tid & 63) == 0) red[tid >> 6] = v;
  __syncthreads();
  if (tid == 0) blockSums[blockIdx.x] = red[0] + red[1] + red[2] + red[3];
}

__global__ __launch_bounds__(256) void scan_pass2(
    const int* __restrict__ blockSums, int* __restrict__ blockOffs)
{
  __shared__ int part[256];
  int tid = threadIdx.x;
  int v = (tid < SCAN_BLOCKS) ? blockSums[tid] : 0;
  part[tid] = v;
  __syncthreads();
  for (int off = 1; off < 256; off <<= 1) {
    int t = 0;
    if (tid >= off) t = part[tid - off];
    __syncthreads();
    if (tid >= off) part[tid] += t;
    __syncthreads();
  }
  blockOffs[tid] = (tid == 0) ? 0 : part[tid - 1];
}

__global__ __launch_bounds__(256) void scan_pass3(
    const int* __restrict__ deg, const int* __restrict__ blockOffs,
    int* __restrict__ rowptr, int* __restrict__ cursor)
{
  __shared__ int part[256];
  int tid = threadIdx.x;
  int idx = blockIdx.x * 256 + tid;
  int v = (idx < NN) ? deg[idx] : 0;
  part[tid] = v;
  __syncthreads();
  for (int off = 1; off < 256; off <<= 1) {
    int t = 0;
    if (tid >= off) t = part[tid - off];
    __syncthreads();
    if (tid >= off) part[tid] += t;
    __syncthreads();
  }
  int excl = (tid == 0) ? 0 : part[tid - 1];
  int val = blockOffs[blockIdx.x] + excl;
  if (idx < NN) { rowptr[idx] = val; cursor[idx] = val; }
  if (idx == 0) rowptr[NN] = NE;
}

__global__ __launch_bounds__(256) void fill_permute_kernel(
    const int* __restrict__ srcI, const int* __restrict__ dstI,
    const float* __restrict__ ea, int* __restrict__ cursor,
    int* __restrict__ srcP, int* __restrict__ dstP,
    float* __restrict__ eaP)
{
  int e = blockIdx.x * 256 + threadIdx.x;
  if (e < NE) {
    int d = dstI[e];
    int pos = atomicAdd(&cursor[d], 1);
    srcP[pos] = srcI[e];
    dstP[pos] = d;
    *(float4*)&eaP[(size_t)pos * 4] = *(const float4*)&ea[(size_t)e * 4];
  }
}

// ---------------------------------------------------------------------------
// gemm_dual_mfma: Hd = h @ W[0:64], Hs = h @ W[64:128] (bf16 out, MFMA)
// ---------------------------------------------------------------------------
__global__ __launch_bounds__(256) void gemm_dual_mfma(
    const float* __restrict__ h, const float* __restrict__ W, // 132x64
    unsigned short* __restrict__ Hd, unsigned short* __restrict__ Hs)
{
  __shared__ __align__(16) unsigned short Wt_s[2 * 64 * 72];  // [half][n][k]

  const int tid = threadIdx.x;
  const int lane = tid & 63;
  const int wave = tid >> 6;
  const int nn = lane & 15;
  const int kq = lane >> 4;

#pragma unroll
  for (int i = 0; i < 32; ++i) {
    int idx = i * 256 + tid;          // 8192 = 2*64*64
    int half = idx >> 12;
    int rem = idx & 4095;
    int k = rem >> 6, n = rem & 63;
    Wt_s[half * 4608 + n * 72 + k] = f2b(W[idx]);
  }
  __syncthreads();

  s16x8 bfrag[2][4][2];  // [out][nt][kc]
#pragma unroll
  for (int o = 0; o < 2; ++o)
#pragma unroll
    for (int nt = 0; nt < 4; ++nt)
#pragma unroll
      for (int kc = 0; kc < 2; ++kc) {
        const unsigned short* p =
            &Wt_s[o * 4608 + (nt * 16 + nn) * 72 + kc * 32 + kq * 8];
#pragma unroll
        for (int j = 0; j < 8; ++j) bfrag[o][nt][kc][j] = (short)p[j];
      }

  const int rbase = blockIdx.x * 128 + wave * 32;

  f32x4 acc[2][2][4];  // [out][rt][nt]
#pragma unroll
  for (int o = 0; o < 2; ++o)
#pragma unroll
    for (int rt = 0; rt < 2; ++rt)
#pragma unroll
      for (int nt = 0; nt < 4; ++nt) acc[o][rt][nt] = (f32x4){0.f, 0.f, 0.f, 0.f};

#pragma unroll
  for (int rt = 0; rt < 2; ++rt) {
    int row = rbase + rt * 16 + nn;
    int rowc = row < NN ? row : NN - 1;
#pragma unroll
    for (int kc = 0; kc < 2; ++kc) {
      s16x8 af = frag_from_f32(&h[(size_t)rowc * 64 + kc * 32 + kq * 8]);
#pragma unroll
      for (int o = 0; o < 2; ++o)
#pragma unroll
        for (int nt = 0; nt < 4; ++nt)
          acc[o][rt][nt] = __builtin_amdgcn_mfma_f32_16x16x32_bf16(
              af, bfrag[o][nt][kc], acc[o][rt][nt], 0, 0, 0);
    }
  }

#pragma unroll
  for (int rt = 0; rt < 2; ++rt)
#pragma unroll
    for (int nt = 0; nt < 4; ++nt) {
      int col = nt * 16 + nn;
#pragma unroll
      for (int reg = 0; reg < 4; ++reg) {
        int row = rbase + rt * 16 + kq * 4 + reg;
        if (row < NN) {
          Hd[(size_t)row * 64 + col] = f2b(acc[0][rt][nt][reg]);
          Hs[(size_t)row * 64 + col] = f2b(acc[1][rt][nt][reg]);
        }
      }
    }
}

// ---------------------------------------------------------------------------
// edge_stats: accumulate sum/sumsq of t1 = Hd[dstP]+Hs[srcP]+eaP@Wb+b1
// WITHOUT materializing t1. 8 lanes/edge, 4x grid-stride unroll.
// ---------------------------------------------------------------------------
__global__ __launch_bounds__(256) void edge_stats(
    const unsigned short* __restrict__ Hd, const unsigned short* __restrict__ Hs,
    const float* __restrict__ eaP, const int* __restrict__ srcP,
    const int* __restrict__ dstP, const float* __restrict__ Wb, // 4x64
    const float* __restrict__ bias, float* __restrict__ outStats)
{
  __shared__ float red_s[128];
  const int tid = threadIdx.x;
  const int c0 = (tid & 7) * 8;
  float bv[8], w0[8], w1[8], w2[8], w3[8];
#pragma unroll
  for (int j = 0; j < 8; ++j) {
    bv[j] = bias[c0 + j];
    w0[j] = Wb[0 * 64 + c0 + j];
    w1[j] = Wb[1 * 64 + c0 + j];
    w2[j] = Wb[2 * 64 + c0 + j];
    w3[j] = Wb[3 * 64 + c0 + j];
  }

  float s[8], s2[8];
#pragma unroll
  for (int j = 0; j < 8; ++j) { s[j] = 0.f; s2[j] = 0.f; }

  const int e0 = (blockIdx.x * 256 + tid) >> 3;
  const int estep = (gridDim.x * 256) >> 3;

  for (int e = e0; e < NE; e += 4 * estep) {
    bool has[4];
    uint4 hd[4], hs[4];
    float4 av[4];
#pragma unroll
    for (int u = 0; u < 4; ++u) {
      int ee = e + u * estep;
      has[u] = ee < NE;
      int ec = has[u] ? ee : e;
      int si = srcP[ec], di = dstP[ec];
      av[u] = *(const float4*)&eaP[(size_t)ec * 4];
      hd[u] = *(const uint4*)&Hd[(size_t)di * 64 + c0];
      hs[u] = *(const uint4*)&Hs[(size_t)si * 64 + c0];
    }
#pragma unroll
    for (int u = 0; u < 4; ++u) {
      if (!has[u]) continue;
      const unsigned hdw[4] = {hd[u].x, hd[u].y, hd[u].z, hd[u].w};
      const unsigned hsw[4] = {hs[u].x, hs[u].y, hs[u].z, hs[u].w};
#pragma unroll
      for (int d = 0; d < 4; ++d) {
        union { unsigned uu; float f; } a0, a1, b0, b1u;
        a0.uu = (hdw[d] & 0xffffu) << 16; a1.uu = hdw[d] & 0xffff0000u;
        b0.uu = (hsw[d] & 0xffffu) << 16; b1u.uu = hsw[d] & 0xffff0000u;
        int j0 = d * 2, j1 = d * 2 + 1;
        float y0 = a0.f + b0.f + bv[j0] + av[u].x * w0[j0] + av[u].y * w1[j0] + av[u].z * w2[j0] + av[u].w * w3[j0];
        float y1 = a1.f + b1u.f + bv[j1] + av[u].x * w0[j1] + av[u].y * w1[j1] + av[u].z * w2[j1] + av[u].w * w3[j1];
        s[j0] += y0; s2[j0] += y0 * y0;
        s[j1] += y1; s2[j1] += y1 * y1;
      }
    }
  }
#pragma unroll
  for (int j = 0; j < 8; ++j) {
    s[j] += __shfl_xor(s[j], 8, 64);
    s[j] += __shfl_xor(s[j], 16, 64);
    s[j] += __shfl_xor(s[j], 32, 64);
    s2[j] += __shfl_xor(s2[j], 8, 64);
    s2[j] += __shfl_xor(s2[j], 16, 64);
    s2[j] += __shfl_xor(s2[j], 32, 64);
  }
  if (tid < 128) red_s[tid] = 0.f;
  __syncthreads();
  if ((tid & 63) < 8) {
#pragma unroll
    for (int j = 0; j < 8; ++j) {
      atomicAdd(&red_s[c0 + j], s[j]);
      atomicAdd(&red_s[64 + c0 + j], s2[j]);
    }
  }
  __syncthreads();
  if (tid < 128) atomicAdd(&outStats[tid], red_s[tid]);
}

// ---------------------------------------------------------------------------
// gemm_fused_edge: t2 = relu(bn1(t1_onthefly)) @ W2 + b2  (bf16 out, MFMA)
// Phase 1: recompute t1 rows (gathers), apply BN1+ReLU (scale folded into
//   Wb/bias), write bf16 A-tile (256x64) to LDS.
// Phase 2: MFMA from LDS A-frags, b2 bias, st1 stats epilogue.
// Eliminates the t1 global round-trip entirely.
// ---------------------------------------------------------------------------
__global__ __launch_bounds__(256) void gemm_fused_edge(
    const unsigned short* __restrict__ Hd, const unsigned short* __restrict__ Hs,
    const float* __restrict__ eaP, const int* __restrict__ srcP,
    const int* __restrict__ dstP,
    const float* __restrict__ Wb,     // 4 x 64 (W1 bottom)
    const float* __restrict__ b1,
    const float* __restrict__ inStats,// st0
    const float* __restrict__ inG,
    const float* __restrict__ inBe,
    float invM_in,
    const float* __restrict__ W2,     // 64 x 64
    const float* __restrict__ b2,
    unsigned short* __restrict__ outp,// t2, M x 64 bf16
    float* __restrict__ outStats,     // st1
    int M)
{
  __shared__ __align__(16) unsigned short A_s[256 * 72];
  __shared__ __align__(16) unsigned short Wt_s[64 * 72];
  __shared__ float scale_s[64];
  __shared__ float cb_s[64];          // scale*b1 + shift
  __shared__ float red_s[128];

  const int tid = threadIdx.x;
  const int lane = tid & 63;
  const int wave = tid >> 6;
  const int nn = lane & 15;
  const int kq = lane >> 4;
  const int rbase = blockIdx.x * 256;

  if (tid < 64) {
    float mean = inStats[tid] * invM_in;
    float var = inStats[64 + tid] * invM_in - mean * mean;
    float sc = inG[tid] * rsqrtf(var + EPSV);
    scale_s[tid] = sc;
    cb_s[tid] = sc * b1[tid] + (inBe[tid] - mean * sc);
  }
#pragma unroll
  for (int i = 0; i < 16; ++i) {
    int idx = i * 256 + tid;
    int k = idx >> 6, n = idx & 63;
    Wt_s[n * 72 + k] = f2b(W2[idx]);
  }
  __syncthreads();

  // ---- phase 1: A-tile into LDS ----
  {
    const int c0 = (tid & 7) * 8;
    const int erow = tid >> 3;          // 0..31
    float sc8[8], cb8[8], w0[8], w1[8], w2v[8], w3[8];
#pragma unroll
    for (int j = 0; j < 8; ++j) {
      float sc = scale_s[c0 + j];
      sc8[j] = sc;
      cb8[j] = cb_s[c0 + j];
      w0[j] = sc * Wb[0 * 64 + c0 + j];
      w1[j] = sc * Wb[1 * 64 + c0 + j];
      w2v[j] = sc * Wb[2 * 64 + c0 + j];
      w3[j] = sc * Wb[3 * 64 + c0 + j];
    }
#pragma unroll
    for (int it = 0; it < 8; it += 2) {
      int rowA = erow + 32 * it;
      int rowB = erow + 32 * (it + 1);
      int rA = rbase + rowA, rB = rbase + rowB;
      int rAc = rA < M ? rA : M - 1;
      int rBc = rB < M ? rB : M - 1;
      int siA = srcP[rAc], diA = dstP[rAc];
      int siB = srcP[rBc], diB = dstP[rBc];
      float4 avA = *(const float4*)&eaP[(size_t)rAc * 4];
      float4 avB = *(const float4*)&eaP[(size_t)rBc * 4];
      uint4 hdA = *(const uint4*)&Hd[(size_t)diA * 64 + c0];
      uint4 hsA = *(const uint4*)&Hs[(size_t)siA * 64 + c0];
      uint4 hdB = *(const uint4*)&Hd[(size_t)diB * 64 + c0];
      uint4 hsB = *(const uint4*)&Hs[(size_t)siB * 64 + c0];

      unsigned short oA[8], oB[8];
      {
        const unsigned hdw[4] = {hdA.x, hdA.y, hdA.z, hdA.w};
        const unsigned hsw[4] = {hsA.x, hsA.y, hsA.z, hsA.w};
#pragma unroll
        for (int d = 0; d < 4; ++d) {
          union { unsigned uu; float f; } a0, a1, b0, b1u;
          a0.uu = (hdw[d] & 0xffffu) << 16; a1.uu = hdw[d] & 0xffff0000u;
          b0.uu = (hsw[d] & 0xffffu) << 16; b1u.uu = hsw[d] & 0xffff0000u;
          int j0 = d * 2, j1 = d * 2 + 1;
          float y0 = sc8[j0] * (a0.f + b0.f) + cb8[j0] + avA.x * w0[j0] + avA.y * w1[j0] + avA.z * w2v[j0] + avA.w * w3[j0];
          float y1 = sc8[j1] * (a1.f + b1u.f) + cb8[j1] + avA.x * w0[j1] + avA.y * w1[j1] + avA.z * w2v[j1] + avA.w * w3[j1];
          oA[j0] = f2b(fmaxf(y0, 0.f));
          oA[j1] = f2b(fmaxf(y1, 0.f));
        }
      }
      {
        const unsigned hdw[4] = {hdB.x, hdB.y, hdB.z, hdB.w};
        const unsigned hsw[4] = {hsB.x, hsB.y, hsB.z, hsB.w};
#pragma unroll
        for (int d = 0; d < 4; ++d) {
          union { unsigned uu; float f; } a0, a1, b0, b1u;
          a0.uu = (hdw[d] & 0xffffu) << 16; a1.uu = hdw[d] & 0xffff0000u;
          b0.uu = (hsw[d] & 0xffffu) << 16; b1u.uu = hsw[d] & 0xffff0000u;
          int j0 = d * 2, j1 = d * 2 + 1;
          float y0 = sc8[j0] * (a0.f + b0.f) + cb8[j0] + avB.x * w0[j0] + avB.y * w1[j0] + avB.z * w2v[j0] + avB.w * w3[j0];
          float y1 = sc8[j1] * (a1.f + b1u.f) + cb8[j1] + avB.x * w0[j1] + avB.y * w1[j1] + avB.z * w2v[j1] + avB.w * w3[j1];
          oB[j0] = f2b(fmaxf(y0, 0.f));
          oB[j1] = f2b(fmaxf(y1, 0.f));
        }
      }
      *(uint4*)&A_s[rowA * 72 + c0] = *(const uint4*)oA;
      *(uint4*)&A_s[rowB * 72 + c0] = *(const uint4*)oB;
    }
  }
  __syncthreads();

  // ---- phase 2: MFMA from LDS ----
  s16x8 bfrag[4][2];
#pragma unroll
  for (int nt = 0; nt < 4; ++nt)
#pragma unroll
    for (int kc = 0; kc < 2; ++kc)
      bfrag[nt][kc] = *(const s16x8*)&Wt_s[(nt * 16 + nn) * 72 + kc * 32 + kq * 8];

  f32x4 acc[4][4];
#pragma unroll
  for (int rt = 0; rt < 4; ++rt)
#pragma unroll
    for (int nt = 0; nt < 4; ++nt) acc[rt][nt] = (f32x4){0.f, 0.f, 0.f, 0.f};

  const int rw = wave * 64;
#pragma unroll
  for (int rt = 0; rt < 4; ++rt) {
    int rloc = rw + rt * 16 + nn;
#pragma unroll
    for (int kc = 0; kc < 2; ++kc) {
      s16x8 af = *(const s16x8*)&A_s[rloc * 72 + kc * 32 + kq * 8];
#pragma unroll
      for (int nt = 0; nt < 4; ++nt)
        acc[rt][nt] = __builtin_amdgcn_mfma_f32_16x16x32_bf16(
            af, bfrag[nt][kc], acc[rt][nt], 0, 0, 0);
    }
  }

  float bcol[4];
#pragma unroll
  for (int nt = 0; nt < 4; ++nt) bcol[nt] = b2[nt * 16 + nn];

  float s[4] = {0.f, 0.f, 0.f, 0.f};
  float s2[4] = {0.f, 0.f, 0.f, 0.f};
#pragma unroll
  for (int rt = 0; rt < 4; ++rt)
#pragma unroll
    for (int nt = 0; nt < 4; ++nt) {
      int col = nt * 16 + nn;
#pragma unroll
      for (int reg = 0; reg < 4; ++reg) {
        int row = rbase + rw + rt * 16 + kq * 4 + reg;
        if (row < M) {
          float y = acc[rt][nt][reg] + bcol[nt];
          outp[(size_t)row * 64 + col] = f2b(y);
          s[nt] += y; s2[nt] += y * y;
        }
      }
    }
#pragma unroll
  for (int nt = 0; nt < 4; ++nt) {
    s[nt] += __shfl_xor(s[nt], 16, 64);
    s[nt] += __shfl_xor(s[nt], 32, 64);
    s2[nt] += __shfl_xor(s2[nt], 16, 64);
    s2[nt] += __shfl_xor(s2[nt], 32, 64);
  }
  if (tid < 128) red_s[tid] = 0.f;
  __syncthreads();
  if (lane < 16) {
#pragma unroll
    for (int nt = 0; nt < 4; ++nt) {
      atomicAdd(&red_s[nt * 16 + nn], s[nt]);
      atomicAdd(&red_s[64 + nt * 16 + nn], s2[nt]);
    }
  }
  __syncthreads();
  if (tid < 128) atomicAdd(&outStats[tid], red_s[tid]);
}

// ---------------------------------------------------------------------------
// gemm64_bn_mfma (node path): out = relu(bn(A)) @ W + b — bf16, in-place ok.
// 64 rows per wave (256-row block), 8 independent A-loads in flight/lane.
// ---------------------------------------------------------------------------
__global__ __launch_bounds__(256) void gemm64_bn_mfma(
    const unsigned short* A0,         // bf16 M x 64 (may alias outp)
    const float* __restrict__ W,      // 64 x 64 fp32
    const float* __restrict__ bias,
    const float* __restrict__ inStats,
    const float* __restrict__ inG,
    const float* __restrict__ inBe,
    float invM_in,
    unsigned short* outp,             // bf16 M x 64
    float* __restrict__ outStats,
    int M)
{
  __shared__ __align__(16) unsigned short Wt_s[64 * 72];
  __shared__ float scale_s[64];
  __shared__ float shift_s[64];
  __shared__ float red_s[128];

  const int tid = threadIdx.x;
  const int lane = tid & 63;
  const int wave = tid >> 6;
  const int nn = lane & 15;
  const int kq = lane >> 4;

  if (tid < 64) {
    float mean = inStats[tid] * invM_in;
    float var = inStats[64 + tid] * invM_in - mean * mean;
    float sc = inG[tid] * rsqrtf(var + EPSV);
    scale_s[tid] = sc;
    shift_s[tid] = inBe[tid] - mean * sc;
  }
#pragma unroll
  for (int i = 0; i < 16; ++i) {
    int idx = i * 256 + tid;
    int k = idx >> 6, n = idx & 63;
    Wt_s[n * 72 + k] = f2b(W[idx]);
  }
  __syncthreads();

  s16x8 bfrag[4][2];
#pragma unroll
  for (int nt = 0; nt < 4; ++nt)
#pragma unroll
    for (int kc = 0; kc < 2; ++kc)
      bfrag[nt][kc] = *(const s16x8*)&Wt_s[(nt * 16 + nn) * 72 + kc * 32 + kq * 8];

  float scf[2][8], shf[2][8];
#pragma unroll
  for (int kc = 0; kc < 2; ++kc) {
    int k0 = kc * 32 + kq * 8;
    float4 a = *(const float4*)&scale_s[k0];
    float4 b = *(const float4*)&scale_s[k0 + 4];
    float4 c = *(const float4*)&shift_s[k0];
    float4 d = *(const float4*)&shift_s[k0 + 4];
    scf[kc][0] = a.x; scf[kc][1] = a.y; scf[kc][2] = a.z; scf[kc][3] = a.w;
    scf[kc][4] = b.x; scf[kc][5] = b.y; scf[kc][6] = b.z; scf[kc][7] = b.w;
    shf[kc][0] = c.x; shf[kc][1] = c.y; shf[kc][2] = c.z; shf[kc][3] = c.w;
    shf[kc][4] = d.x; shf[kc][5] = d.y; shf[kc][6] = d.z; shf[kc][7] = d.w;
  }

  const int rbase = blockIdx.x * 256 + wave * 64;

  f32x4 acc[4][4];
#pragma unroll
  for (int rt = 0; rt < 4; ++rt)
#pragma unroll
    for (int nt = 0; nt < 4; ++nt) acc[rt][nt] = (f32x4){0.f, 0.f, 0.f, 0.f};

  uint4 raw[4][2];
#pragma unroll
  for (int rt = 0; rt < 4; ++rt) {
    int row = rbase + rt * 16 + nn;
    int rowc = row < M ? row : M - 1;
#pragma unroll
    for (int kc = 0; kc < 2; ++kc)
      raw[rt][kc] = *(const uint4*)&A0[(size_t)rowc * 64 + kc * 32 + kq * 8];
  }

#pragma unroll
  for (int rt = 0; rt < 4; ++rt) {
#pragma unroll
    for (int kc = 0; kc < 2; ++kc) {
      unsigned wbits[4] = {raw[rt][kc].x, raw[rt][kc].y, raw[rt][kc].z, raw[rt][kc].w};
      s16x8 af;
#pragma unroll
      for (int d = 0; d < 4; ++d) {
        union { unsigned u; float f; } lo, hi;
        lo.u = (wbits[d] & 0xffffu) << 16;
        hi.u = wbits[d] & 0xffff0000u;
        int j0 = d * 2, j1 = d * 2 + 1;
        af[j0] = (short)f2b(fmaxf(fmaf(scf[kc][j0], lo.f, shf[kc][j0]), 0.f));
        af[j1] = (short)f2b(fmaxf(fmaf(scf[kc][j1], hi.f, shf[kc][j1]), 0.f));
      }
#pragma unroll
      for (int nt = 0; nt < 4; ++nt)
        acc[rt][nt] = __builtin_amdgcn_mfma_f32_16x16x32_bf16(
            af, bfrag[nt][kc], acc[rt][nt], 0, 0, 0);
    }
  }

  float bcol[4];
#pragma unroll
  for (int nt = 0; nt < 4; ++nt) bcol[nt] = bias[nt * 16 + nn];

  float s[4] = {0.f, 0.f, 0.f, 0.f};
  float s2[4] = {0.f, 0.f, 0.f, 0.f};
#pragma unroll
  for (int rt = 0; rt < 4; ++rt)
#pragma unroll
    for (int nt = 0; nt < 4; ++nt) {
      int col = nt * 16 + nn;
#pragma unroll
      for (int reg = 0; reg < 4; ++reg) {
        int row = rbase + rt * 16 + kq * 4 + reg;
        if (row < M) {
          float y = acc[rt][nt][reg] + bcol[nt];
          outp[(size_t)row * 64 + col] = f2b(y);
          s[nt] += y; s2[nt] += y * y;
        }
      }
    }
#pragma unroll
  for (int nt = 0; nt < 4; ++nt) {
    s[nt] += __shfl_xor(s[nt], 16, 64);
    s[nt] += __shfl_xor(s[nt], 32, 64);
    s2[nt] += __shfl_xor(s2[nt], 16, 64);
    s2[nt] += __shfl_xor(s2[nt], 32, 64);
  }
  if (tid < 128) red_s[tid] = 0.f;
  __syncthreads();
  if (lane < 16) {
#pragma unroll
    for (int nt = 0; nt < 4; ++nt) {
      atomicAdd(&red_s[nt * 16 + nn], s[nt]);
      atomicAdd(&red_s[64 + nt * 16 + nn], s2[nt]);
    }
  }
  __syncthreads();
  if (tid < 128) atomicAdd(&outStats[tid], red_s[tid]);
}

// ---------------------------------------------------------------------------
// gemm_concat_mfma: u1 = [h(fp32)|aggr(bf16)] @ W(128x64) + b (bf16 out)
// ---------------------------------------------------------------------------
__global__ __launch_bounds__(256) void gemm_concat_mfma(
    const float* __restrict__ A0,            // h fp32
    const unsigned short* __restrict__ A1b,  // aggr bf16
    const float* __restrict__ W,             // 128 x 64
    const float* __restrict__ bias,
    unsigned short* __restrict__ outp,       // u1 bf16
    float* __restrict__ outStats,
    int M)
{
  __shared__ __align__(16) unsigned short Wt_s[64 * 136];
  __shared__ float red_s[128];

  const int tid = threadIdx.x;
  const int lane = tid & 63;
  const int wave = tid >> 6;
  const int nn = lane & 15;
  const int kq = lane >> 4;

#pragma unroll
  for (int i = 0; i < 32; ++i) {
    int idx = i * 256 + tid;          // 8192
    int k = idx >> 6, n = idx & 63;
    Wt_s[n * 136 + k] = f2b(W[idx]);
  }
  __syncthreads();

  s16x8 bfrag[4][4];  // [nt][kc]
#pragma unroll
  for (int nt = 0; nt < 4; ++nt)
#pragma unroll
    for (int kc = 0; kc < 4; ++kc) {
      const unsigned short* p = &Wt_s[(nt * 16 + nn) * 136 + kc * 32 + kq * 8];
#pragma unroll
      for (int j = 0; j < 8; ++j) bfrag[nt][kc][j] = (short)p[j];
    }

  const int rbase = blockIdx.x * 128 + wave * 32;

  f32x4 acc[2][4];
#pragma unroll
  for (int rt = 0; rt < 2; ++rt)
#pragma unroll
    for (int nt = 0; nt < 4; ++nt) acc[rt][nt] = (f32x4){0.f, 0.f, 0.f, 0.f};

#pragma unroll
  for (int rt = 0; rt < 2; ++rt) {
    int row = rbase + rt * 16 + nn;
    int rowc = row < M ? row : M - 1;
#pragma unroll
    for (int kc = 0; kc < 4; ++kc) {
      s16x8 af;
      if (kc < 2) {
        af = frag_from_f32(&A0[(size_t)rowc * 64 + kc * 32 + kq * 8]);
      } else {
        af = *(const s16x8*)&A1b[(size_t)rowc * 64 + (kc - 2) * 32 + kq * 8];
      }
#pragma unroll
      for (int nt = 0; nt < 4; ++nt)
        acc[rt][nt] = __builtin_amdgcn_mfma_f32_16x16x32_bf16(
            af, bfrag[nt][kc], acc[rt][nt], 0, 0, 0);
    }
  }

  float bcol[4];
#pragma unroll
  for (int nt = 0; nt < 4; ++nt) bcol[nt] = bias[nt * 16 + nn];

  float s[4] = {0.f, 0.f, 0.f, 0.f};
  float s2[4] = {0.f, 0.f, 0.f, 0.f};
#pragma unroll
  for (int rt = 0; rt < 2; ++rt)
#pragma unroll
    for (int nt = 0; nt < 4; ++nt) {
      int col = nt * 16 + nn;
#pragma unroll
      for (int reg = 0; reg < 4; ++reg) {
        int row = rbase + rt * 16 + kq * 4 + reg;
        if (row < M) {
          float y = acc[rt][nt][reg] + bcol[nt];
          outp[(size_t)row * 64 + col] = f2b(y);
          s[nt] += y; s2[nt] += y * y;
        }
      }
    }
#pragma unroll
  for (int nt = 0; nt < 4; ++nt) {
    s[nt] += __shfl_xor(s[nt], 16, 64);
    s[nt] += __shfl_xor(s[nt], 32, 64);
    s2[nt] += __shfl_xor(s2[nt], 16, 64);
    s2[nt] += __shfl_xor(s2[nt], 32, 64);
  }
  if (tid < 128) red_s[tid] = 0.f;
  __syncthreads();
  if (lane < 16) {
#pragma unroll
    for (int nt = 0; nt < 4; ++nt) {
      atomicAdd(&red_s[nt * 16 + nn], s[nt]);
      atomicAdd(&red_s[64 + nt * 16 + nn], s2[nt]);
    }
  }
  __syncthreads();
  if (tid < 128) atomicAdd(&outStats[tid], red_s[tid]);
}

// ---------------------------------------------------------------------------
// aggregate (sequential CSR stream): aggr[n] = sum relu(bn(t2[p]))
// ---------------------------------------------------------------------------
__global__ __launch_bounds__(256) void aggregate_kernel(
    const unsigned short* __restrict__ t2, const int* __restrict__ rowptr,
    const float* __restrict__ stats, const float* __restrict__ g,
    const float* __restrict__ be, float invM,
    unsigned short* __restrict__ aggr)
{
  int node = (blockIdx.x * 256 + threadIdx.x) >> 6;
  int lane = threadIdx.x & 63;
  if (node >= NN) return;
  float mean = stats[lane] * invM;
  float var = stats[64 + lane] * invM - mean * mean;
  float sc = g[lane] * rsqrtf(var + EPSV);
  float sh = be[lane] - mean * sc;
  int lo = rowptr[node], hi = rowptr[node + 1];
  float acc = 0.f;
  int i = lo;
  for (; i + 3 < hi; i += 4) {
    float v1 = b2f(t2[(size_t)(i + 0) * 64 + lane]);
    float v2 = b2f(t2[(size_t)(i + 1) * 64 + lane]);
    float v3 = b2f(t2[(size_t)(i + 2) * 64 + lane]);
    float v4 = b2f(t2[(size_t)(i + 3) * 64 + lane]);
    acc += fmaxf(fmaf(sc, v1, sh), 0.f) + fmaxf(fmaf(sc, v2, sh), 0.f) +
           fmaxf(fmaf(sc, v3, sh), 0.f) + fmaxf(fmaf(sc, v4, sh), 0.f);
  }
  for (; i < hi; ++i)
    acc += fmaxf(fmaf(sc, b2f(t2[(size_t)i * 64 + lane]), sh), 0.f);
  aggr[(size_t)node * 64 + lane] = f2b(acc);
}

// ---------------------------------------------------------------------------
// residual: h += relu(bn(u2_bf16))
// ---------------------------------------------------------------------------
__global__ __launch_bounds__(256) void residual_kernel(
    const unsigned short* __restrict__ u2, const float* __restrict__ stats,
    const float* __restrict__ g, const float* __restrict__ be,
    float invM, float* __restrict__ h)
{
  int gid = blockIdx.x * 256 + threadIdx.x;
  if (gid >= NN * 16) return;
  int c = (gid & 15) * 4;
  ushort4 v4 = *(const ushort4*)&u2[(size_t)gid * 4];
  float4 hv = *(const float4*)&h[(size_t)gid * 4];
  const unsigned short vu[4] = {v4.x, v4.y, v4.z, v4.w};
  float* hp = (float*)&hv;
#pragma unroll
  for (int j = 0; j < 4; ++j) {
    float mean = stats[c + j] * invM;
    float var = stats[64 + c + j] * invM - mean * mean;
    float sc = g[c + j] * rsqrtf(var + EPSV);
    float sh = be[c + j] - mean * sc;
    hp[j] += fmaxf(fmaf(sc, b2f(vu[j]), sh), 0.f);
  }
  *(float4*)&h[(size_t)gid * 4] = hv;
}

// ---------------------------------------------------------------------------
// pool: partial per-graph column sums, then tiny final with prediction head
// ---------------------------------------------------------------------------
constexpr int POOL_NPB = 128;  // nodes per block

__global__ __launch_bounds__(256) void pool_partial(
    const float* __restrict__ h, const int* __restrict__ batch,
    float* __restrict__ sums)  // NG x 64
{
  int lane = threadIdx.x & 63;
  int wave = threadIdx.x >> 6;
  int base = blockIdx.x * POOL_NPB;
  float acc = 0.f;
  int gcur = -1;
  for (int i = wave; i < POOL_NPB; i += 4) {
    int n = base + i;
    if (n >= NN) break;
    int g = batch[n];
    if (g != gcur) {
      if (gcur >= 0) atomicAdd(&sums[gcur * 64 + lane], acc);
      gcur = g;
      acc = 0.f;
    }
    acc += h[(size_t)n * 64 + lane];
  }
  if (gcur >= 0) atomicAdd(&sums[gcur * 64 + lane], acc);
}

DEV int lower_bound_i(const int* __restrict__ a, int n, int v) {
  int lo = 0, hi = n;
  while (lo < hi) {
    int m = (lo + hi) >> 1;
    if (a[m] < v) lo = m + 1; else hi = m;
  }
  return lo;
}

__global__ __launch_bounds__(64) void pool_final(
    const float* __restrict__ sums, const int* __restrict__ batch,
    const float* __restrict__ predW, const float* __restrict__ predB,
    float* __restrict__ out)
{
  int g = blockIdx.x;
  int lane = threadIdx.x;
  int lo = lower_bound_i(batch, NN, g);
  int hi = lower_bound_i(batch, NN, g + 1);
  float cnt = fmaxf((float)(hi - lo), 1.0f);
  float p = sums[g * 64 + lane] / cnt * predW[lane];
#pragma unroll
  for (int off = 32; off > 0; off >>= 1) p += __shfl_down(p, off, 64);
  if (lane == 0) out[g] = p + predB[0];
}

// ---------------------------------------------------------------------------
extern "C" void kernel_launch(void* const* d_in, const int* in_sizes, int n_in,
                              void* d_out, int out_size, void* d_ws, size_t ws_size,
                              hipStream_t stream)
{
  (void)in_sizes; (void)n_in; (void)out_size; (void)ws_size;

  const float* x        = (const float*)d_in[0];
  const float* edge_attr= (const float*)d_in[1];
  const int*   eidx     = (const int*)d_in[2];
  const int*   batch    = (const int*)d_in[3];
  const float* linW     = (const float*)d_in[4];
  const float* linB     = (const float*)d_in[5];
  const float* msgW1    = (const float*)d_in[6];
  const float* msgB1    = (const float*)d_in[7];
  const float* msgG1    = (const float*)d_in[8];
  const float* msgBe1   = (const float*)d_in[9];
  const float* msgW2    = (const float*)d_in[10];
  const float* msgB2    = (const float*)d_in[11];
  const float* msgG2    = (const float*)d_in[12];
  const float* msgBe2   = (const float*)d_in[13];
  const float* updW1    = (const float*)d_in[14];
  const float* updB1    = (const float*)d_in[15];
  const float* updG1    = (const float*)d_in[16];
  const float* updBe1   = (const float*)d_in[17];
  const float* updW2    = (const float*)d_in[18];
  const float* updB2    = (const float*)d_in[19];
  const float* updG2    = (const float*)d_in[20];
  const float* updBe2   = (const float*)d_in[21];
  const float* predW    = (const float*)d_in[22];
  const float* predB    = (const float*)d_in[23];

  const int* srcI = eidx;        // edge_index[0] = source
  const int* dstI = eidx + NE;   // edge_index[1] = target

  char* p = (char*)d_ws;
  float* h  = (float*)p;            p += (size_t)NN * 64 * 4;
  unsigned short* t2 = (unsigned short*)p; p += (size_t)NE * 64 * 2;
  unsigned short* aggr = (unsigned short*)p; p += (size_t)NN * 64 * 2;
  unsigned short* u1 = (unsigned short*)p;   p += (size_t)NN * 64 * 2;
  unsigned short* Hd = (unsigned short*)p;   p += (size_t)NN * 64 * 2;
  unsigned short* Hs = (unsigned short*)p;   p += (size_t)NN * 64 * 2;
  float* stats = (float*)p;         p += 16 * 128 * 4;
  float* sums = (float*)p;          p += NG * 64 * 4;
  int* deg = (int*)p;               p += (size_t)NN * 4;
  int* cursor = (int*)p;            p += (size_t)NN * 4;
  int* rowptr = (int*)p;            p += (size_t)(NN + 1) * 4;
  int* srcP = (int*)p;              p += (size_t)NE * 4;
  int* dstP = (int*)p;              p += (size_t)NE * 4;
  float* eaP = (float*)p;           p += (size_t)NE * 4 * 4;
  int* blockSums = (int*)p;         p += 256 * 4;
  int* blockOffs = (int*)p;         p += 256 * 4;

  hipMemsetAsync(stats, 0, (16 * 128 + NG * 64) * sizeof(float), stream);
  hipMemsetAsync(deg, 0, NN * sizeof(int), stream);

  hist_kernel<<<(NE + 255) / 256, 256, 0, stream>>>(dstI, deg);
  scan_pass1<<<SCAN_BLOCKS, 256, 0, stream>>>(deg, blockSums);
  scan_pass2<<<1, 256, 0, stream>>>(blockSums, blockOffs);
  scan_pass3<<<SCAN_BLOCKS, 256, 0, stream>>>(deg, blockOffs, rowptr, cursor);
  fill_permute_kernel<<<(NE + 255) / 256, 256, 0, stream>>>(
      srcI, dstI, edge_attr, cursor, srcP, dstP, eaP);

  lin_in_kernel<<<(NN * 64 + 255) / 256, 256, 0, stream>>>(x, linW, linB, h);

  const float invE = 1.0f / (float)NE;
  const float invN = 1.0f / (float)NN;
  const int NB128 = (NN + 127) / 128;         // 391
  const int NB256 = (NN + 255) / 256;         // 196
  const int EB256 = (NE + 255) / 256;         // 1563

  for (int l = 0; l < 4; ++l) {
    float* st0 = stats + (l * 4 + 0) * 128;
    float* st1 = stats + (l * 4 + 1) * 128;
    float* st2 = stats + (l * 4 + 2) * 128;
    float* st3 = stats + (l * 4 + 3) * 128;
    const float* W1 = msgW1 + (size_t)l * 132 * 64;

    // Hd = h @ W1[0:64], Hs = h @ W1[64:128]  (bf16 out, MFMA)
    gemm_dual_mfma<<<NB128, 256, 0, stream>>>(h, W1, Hd, Hs);

    // st0 = stats of t1 (computed on-the-fly, never materialized)
    edge_stats<<<2048, 256, 0, stream>>>(
        Hd, Hs, eaP, srcP, dstP, W1 + 128 * 64, msgB1 + l * 64, st0);

    // t2 = relu(bn1(t1_onthefly)) @ msgW2 + b2 (fused, bf16 out) ; stats(st1)
    gemm_fused_edge<<<EB256, 256, 0, stream>>>(
        Hd, Hs, eaP, srcP, dstP, W1 + 128 * 64, msgB1 + l * 64,
        st0, msgG1 + l * 64, msgBe1 + l * 64, invE,
        msgW2 + (size_t)l * 64 * 64, msgB2 + l * 64,
        t2, st1, NE);

    // aggr[n] = sum relu(bn(t2)) over CSR rows (sequential stream, bf16 out)
    aggregate_kernel<<<(NN * 64 + 255) / 256, 256, 0, stream>>>(
        t2, rowptr, st1, msgG2 + l * 64, msgBe2 + l * 64, invE, aggr);

    // u1 = [h|aggr] @ updW1 + b1 (MFMA, bf16 out) ; stats(st2)
    gemm_concat_mfma<<<NB128, 256, 0, stream>>>(
        h, aggr, updW1 + (size_t)l * 128 * 64, updB1 + l * 64,
        u1, st2, NN);

    // u1 = relu(bn(u1)) @ updW2 + b2 (bf16, in-place, MFMA) ; stats(st3)
    gemm64_bn_mfma<<<NB256, 256, 0, stream>>>(
        u1, updW2 + (size_t)l * 64 * 64, updB2 + l * 64,
        st2, updG1 + l * 64, updBe1 + l * 64, invN,
        u1, st3, NN);

    // h += relu(bn(u1))
    residual_kernel<<<(NN * 16 + 255) / 256, 256, 0, stream>>>(
        u1, st3, updG2 + l * 64, updBe2 + l * 64, invN, h);
  }

  pool_partial<<<(NN + POOL_NPB - 1) / POOL_NPB, 256, 0, stream>>>(h, batch, sums);
  pool_final<<<NG, 64, 0, stream>>>(sums, batch, predW, predB, (float*)d_out);
}

// Round 10
// 783.215 us; speedup vs baseline: 1.2549x; 1.2549x over previous
//
#include <hip/hip_runtime.h>

#define DEV __device__ __forceinline__

constexpr int NN = 50000;   // nodes
constexpr int NE = 400000;  // edges
constexpr int NG = 32;      // graphs
constexpr float EPSV = 1e-5f;
constexpr int SCAN_BLOCKS = 196;  // 196*256 = 50176 >= NN
constexpr int NSHARD = 8;         // stats shards (atomic-contention relief)
constexpr int STB = NSHARD * 128; // floats per BN-stats instance

typedef __attribute__((ext_vector_type(8))) short s16x8;
typedef __attribute__((ext_vector_type(4))) float f32x4;

DEV unsigned short f2b(float f) {  // fp32 -> bf16 RNE (finite inputs)
  union { float f; unsigned u; } x; x.f = f;
  unsigned r = x.u + 0x7fffu + ((x.u >> 16) & 1u);
  return (unsigned short)(r >> 16);
}
DEV float b2f(unsigned short u) {
  union { unsigned u; float f; } x; x.u = ((unsigned)u) << 16; return x.f;
}

DEV s16x8 frag_from_f32(const float* p) {
  const float4 v0 = *(const float4*)p;
  const float4 v1 = *(const float4*)(p + 4);
  s16x8 af;
  af[0] = (short)f2b(v0.x); af[1] = (short)f2b(v0.y);
  af[2] = (short)f2b(v0.z); af[3] = (short)f2b(v0.w);
  af[4] = (short)f2b(v1.x); af[5] = (short)f2b(v1.y);
  af[6] = (short)f2b(v1.z); af[7] = (short)f2b(v1.w);
  return af;
}

// sum the NSHARD shards of a stats instance and produce scale/shift for ch c
DEV void bn_coeff(const float* __restrict__ st, const float* __restrict__ g,
                  const float* __restrict__ be, float invM, int c,
                  float& sc, float& sh) {
  float s = 0.f, s2 = 0.f;
#pragma unroll
  for (int k = 0; k < NSHARD; ++k) {
    s += st[k * 128 + c];
    s2 += st[k * 128 + 64 + c];
  }
  float mean = s * invM;
  float var = s2 * invM - mean * mean;
  sc = g[c] * rsqrtf(var + EPSV);
  sh = be[c] - mean * sc;
}

// ---------------------------------------------------------------------------
// lin_in: h = x @ W(11x64) + b
// ---------------------------------------------------------------------------
__global__ __launch_bounds__(256) void lin_in_kernel(
    const float* __restrict__ x, const float* __restrict__ W,
    const float* __restrict__ b, float* __restrict__ h)
{
  int gid = blockIdx.x * 256 + threadIdx.x;
  if (gid >= NN * 64) return;
  int n = gid >> 6, c = gid & 63;
  float acc = b[c];
#pragma unroll
  for (int k = 0; k < 11; ++k)
    acc = fmaf(x[n * 11 + k], W[k * 64 + c], acc);
  h[gid] = acc;
}

// ---------------------------------------------------------------------------
// CSR build: histogram -> hierarchical exclusive scan -> permuting fill.
// ---------------------------------------------------------------------------
__global__ __launch_bounds__(256) void hist_kernel(
    const int* __restrict__ dstI, int* __restrict__ deg)
{
  int e = blockIdx.x * 256 + threadIdx.x;
  if (e < NE) atomicAdd(&deg[dstI[e]], 1);
}

__global__ __launch_bounds__(256) void scan_pass1(
    const int* __restrict__ deg, int* __restrict__ blockSums)
{
  __shared__ int red[4];
  int tid = threadIdx.x;
  int idx = blockIdx.x * 256 + tid;
  int v = (idx < NN) ? deg[idx] : 0;
#pragma unroll
  for (int off = 32; off > 0; off >>= 1) v += __shfl_down(v, off, 64);
  if ((tid & 63) == 0) red[tid >> 6] = v;
  __syncthreads();
  if (tid == 0) blockSums[blockIdx.x] = red[0] + red[1] + red[2] + red[3];
}

__global__ __launch_bounds__(256) void scan_pass2(
    const int* __restrict__ blockSums, int* __restrict__ blockOffs)
{
  __shared__ int part[256];
  int tid = threadIdx.x;
  int v = (tid < SCAN_BLOCKS) ? blockSums[tid] : 0;
  part[tid] = v;
  __syncthreads();
  for (int off = 1; off < 256; off <<= 1) {
    int t = 0;
    if (tid >= off) t = part[tid - off];
    __syncthreads();
    if (tid >= off) part[tid] += t;
    __syncthreads();
  }
  blockOffs[tid] = (tid == 0) ? 0 : part[tid - 1];
}

__global__ __launch_bounds__(256) void scan_pass3(
    const int* __restrict__ deg, const int* __restrict__ blockOffs,
    int* __restrict__ rowptr, int* __restrict__ cursor)
{
  __shared__ int part[256];
  int tid = threadIdx.x;
  int idx = blockIdx.x * 256 + tid;
  int v = (idx < NN) ? deg[idx] : 0;
  part[tid] = v;
  __syncthreads();
  for (int off = 1; off < 256; off <<= 1) {
    int t = 0;
    if (tid >= off) t = part[tid - off];
    __syncthreads();
    if (tid >= off) part[tid] += t;
    __syncthreads();
  }
  int excl = (tid == 0) ? 0 : part[tid - 1];
  int val = blockOffs[blockIdx.x] + excl;
  if (idx < NN) { rowptr[idx] = val; cursor[idx] = val; }
  if (idx == 0) rowptr[NN] = NE;
}

__global__ __launch_bounds__(256) void fill_permute_kernel(
    const int* __restrict__ srcI, const int* __restrict__ dstI,
    const float* __restrict__ ea, int* __restrict__ cursor,
    int* __restrict__ srcP, int* __restrict__ dstP,
    float* __restrict__ eaP)
{
  int e = blockIdx.x * 256 + threadIdx.x;
  if (e < NE) {
    int d = dstI[e];
    int pos = atomicAdd(&cursor[d], 1);
    srcP[pos] = srcI[e];
    dstP[pos] = d;
    *(float4*)&eaP[(size_t)pos * 4] = *(const float4*)&ea[(size_t)e * 4];
  }
}

// ---------------------------------------------------------------------------
// gemm_dual_mfma: Hd = h @ W[0:64], Hs = h @ W[64:128] (bf16 out, MFMA)
// ---------------------------------------------------------------------------
__global__ __launch_bounds__(256) void gemm_dual_mfma(
    const float* __restrict__ h, const float* __restrict__ W, // 132x64
    unsigned short* __restrict__ Hd, unsigned short* __restrict__ Hs)
{
  __shared__ __align__(16) unsigned short Wt_s[2 * 64 * 72];  // [half][n][k]

  const int tid = threadIdx.x;
  const int lane = tid & 63;
  const int wave = tid >> 6;
  const int nn = lane & 15;
  const int kq = lane >> 4;

#pragma unroll
  for (int i = 0; i < 32; ++i) {
    int idx = i * 256 + tid;          // 8192 = 2*64*64
    int half = idx >> 12;
    int rem = idx & 4095;
    int k = rem >> 6, n = rem & 63;
    Wt_s[half * 4608 + n * 72 + k] = f2b(W[idx]);
  }
  __syncthreads();

  s16x8 bfrag[2][4][2];  // [out][nt][kc]
#pragma unroll
  for (int o = 0; o < 2; ++o)
#pragma unroll
    for (int nt = 0; nt < 4; ++nt)
#pragma unroll
      for (int kc = 0; kc < 2; ++kc) {
        const unsigned short* p =
            &Wt_s[o * 4608 + (nt * 16 + nn) * 72 + kc * 32 + kq * 8];
#pragma unroll
        for (int j = 0; j < 8; ++j) bfrag[o][nt][kc][j] = (short)p[j];
      }

  const int rbase = blockIdx.x * 128 + wave * 32;

  f32x4 acc[2][2][4];  // [out][rt][nt]
#pragma unroll
  for (int o = 0; o < 2; ++o)
#pragma unroll
    for (int rt = 0; rt < 2; ++rt)
#pragma unroll
      for (int nt = 0; nt < 4; ++nt) acc[o][rt][nt] = (f32x4){0.f, 0.f, 0.f, 0.f};

#pragma unroll
  for (int rt = 0; rt < 2; ++rt) {
    int row = rbase + rt * 16 + nn;
    int rowc = row < NN ? row : NN - 1;
#pragma unroll
    for (int kc = 0; kc < 2; ++kc) {
      s16x8 af = frag_from_f32(&h[(size_t)rowc * 64 + kc * 32 + kq * 8]);
#pragma unroll
      for (int o = 0; o < 2; ++o)
#pragma unroll
        for (int nt = 0; nt < 4; ++nt)
          acc[o][rt][nt] = __builtin_amdgcn_mfma_f32_16x16x32_bf16(
              af, bfrag[o][nt][kc], acc[o][rt][nt], 0, 0, 0);
    }
  }

#pragma unroll
  for (int rt = 0; rt < 2; ++rt)
#pragma unroll
    for (int nt = 0; nt < 4; ++nt) {
      int col = nt * 16 + nn;
#pragma unroll
      for (int reg = 0; reg < 4; ++reg) {
        int row = rbase + rt * 16 + kq * 4 + reg;
        if (row < NN) {
          Hd[(size_t)row * 64 + col] = f2b(acc[0][rt][nt][reg]);
          Hs[(size_t)row * 64 + col] = f2b(acc[1][rt][nt][reg]);
        }
      }
    }
}

// ---------------------------------------------------------------------------
// edge_combine: t1[p] = Hd[dstP[p]] + Hs[srcP[p]] + eaP[p]@Wb + b (bf16 out)
// 8 lanes/edge, 16B ops, 2x grid-stride unroll; sharded stats.
// ---------------------------------------------------------------------------
__global__ __launch_bounds__(256) void edge_combine(
    const unsigned short* __restrict__ Hd, const unsigned short* __restrict__ Hs,
    const float* __restrict__ eaP, const int* __restrict__ srcP,
    const int* __restrict__ dstP, const float* __restrict__ Wb, // 4x64
    const float* __restrict__ bias, unsigned short* __restrict__ t1,
    float* __restrict__ outStats)
{
  __shared__ float red_s[128];
  const int tid = threadIdx.x;
  const int c0 = (tid & 7) * 8;
  float bv[8], w0[8], w1[8], w2[8], w3[8];
#pragma unroll
  for (int j = 0; j < 8; ++j) {
    bv[j] = bias[c0 + j];
    w0[j] = Wb[0 * 64 + c0 + j];
    w1[j] = Wb[1 * 64 + c0 + j];
    w2[j] = Wb[2 * 64 + c0 + j];
    w3[j] = Wb[3 * 64 + c0 + j];
  }

  float s[8], s2[8];
#pragma unroll
  for (int j = 0; j < 8; ++j) { s[j] = 0.f; s2[j] = 0.f; }

  const int e0 = (blockIdx.x * 256 + tid) >> 3;
  const int estep = (gridDim.x * 256) >> 3;

  for (int e = e0; e < NE; e += 2 * estep) {
    int eb = e + estep;
    bool hasB = eb < NE;
    int siA = srcP[e], diA = dstP[e];
    float4 avA = *(const float4*)&eaP[(size_t)e * 4];
    uint4 hdA = *(const uint4*)&Hd[(size_t)diA * 64 + c0];
    uint4 hsA = *(const uint4*)&Hs[(size_t)siA * 64 + c0];
    int ebc = hasB ? eb : e;
    int siB = srcP[ebc], diB = dstP[ebc];
    float4 avB = *(const float4*)&eaP[(size_t)ebc * 4];
    uint4 hdB = *(const uint4*)&Hd[(size_t)diB * 64 + c0];
    uint4 hsB = *(const uint4*)&Hs[(size_t)siB * 64 + c0];

    {
      const unsigned hdw[4] = {hdA.x, hdA.y, hdA.z, hdA.w};
      const unsigned hsw[4] = {hsA.x, hsA.y, hsA.z, hsA.w};
      unsigned short ob[8];
#pragma unroll
      for (int d = 0; d < 4; ++d) {
        union { unsigned u; float f; } a0, a1, b0, b1;
        a0.u = (hdw[d] & 0xffffu) << 16; a1.u = hdw[d] & 0xffff0000u;
        b0.u = (hsw[d] & 0xffffu) << 16; b1.u = hsw[d] & 0xffff0000u;
        int j0 = d * 2, j1 = d * 2 + 1;
        float y0 = a0.f + b0.f + bv[j0] + avA.x * w0[j0] + avA.y * w1[j0] + avA.z * w2[j0] + avA.w * w3[j0];
        float y1 = a1.f + b1.f + bv[j1] + avA.x * w0[j1] + avA.y * w1[j1] + avA.z * w2[j1] + avA.w * w3[j1];
        ob[j0] = f2b(y0); ob[j1] = f2b(y1);
        s[j0] += y0; s2[j0] += y0 * y0;
        s[j1] += y1; s2[j1] += y1 * y1;
      }
      *(uint4*)&t1[(size_t)e * 64 + c0] = *(const uint4*)ob;
    }
    if (hasB) {
      const unsigned hdw[4] = {hdB.x, hdB.y, hdB.z, hdB.w};
      const unsigned hsw[4] = {hsB.x, hsB.y, hsB.z, hsB.w};
      unsigned short ob[8];
#pragma unroll
      for (int d = 0; d < 4; ++d) {
        union { unsigned u; float f; } a0, a1, b0, b1;
        a0.u = (hdw[d] & 0xffffu) << 16; a1.u = hdw[d] & 0xffff0000u;
        b0.u = (hsw[d] & 0xffffu) << 16; b1.u = hsw[d] & 0xffff0000u;
        int j0 = d * 2, j1 = d * 2 + 1;
        float y0 = a0.f + b0.f + bv[j0] + avB.x * w0[j0] + avB.y * w1[j0] + avB.z * w2[j0] + avB.w * w3[j0];
        float y1 = a1.f + b1.f + bv[j1] + avB.x * w0[j1] + avB.y * w1[j1] + avB.z * w2[j1] + avB.w * w3[j1];
        ob[j0] = f2b(y0); ob[j1] = f2b(y1);
        s[j0] += y0; s2[j0] += y0 * y0;
        s[j1] += y1; s2[j1] += y1 * y1;
      }
      *(uint4*)&t1[(size_t)eb * 64 + c0] = *(const uint4*)ob;
    }
  }
#pragma unroll
  for (int j = 0; j < 8; ++j) {
    s[j] += __shfl_xor(s[j], 8, 64);
    s[j] += __shfl_xor(s[j], 16, 64);
    s[j] += __shfl_xor(s[j], 32, 64);
    s2[j] += __shfl_xor(s2[j], 8, 64);
    s2[j] += __shfl_xor(s2[j], 16, 64);
    s2[j] += __shfl_xor(s2[j], 32, 64);
  }
  if (tid < 128) red_s[tid] = 0.f;
  __syncthreads();
  if ((tid & 63) < 8) {
#pragma unroll
    for (int j = 0; j < 8; ++j) {
      atomicAdd(&red_s[c0 + j], s[j]);
      atomicAdd(&red_s[64 + c0 + j], s2[j]);
    }
  }
  __syncthreads();
  if (tid < 128)
    atomicAdd(&outStats[(blockIdx.x & (NSHARD - 1)) * 128 + tid], red_s[tid]);
}

// ---------------------------------------------------------------------------
// gemm64_bn_mfma: out = relu(bn(A)) @ W + b — bf16 in/out, MFMA, in-place ok.
// 64 rows per wave (256-row block), 8 independent A-loads in flight/lane.
// Sharded stats in (summed) and out (scattered).
// ---------------------------------------------------------------------------
__global__ __launch_bounds__(256) void gemm64_bn_mfma(
    const unsigned short* A0,         // bf16 M x 64 (may alias outp)
    const float* __restrict__ W,      // 64 x 64 fp32
    const float* __restrict__ bias,
    const float* __restrict__ inStats,
    const float* __restrict__ inG,
    const float* __restrict__ inBe,
    float invM_in,
    unsigned short* outp,             // bf16 M x 64
    float* __restrict__ outStats,
    int M)
{
  __shared__ __align__(16) unsigned short Wt_s[64 * 72];
  __shared__ float scale_s[64];
  __shared__ float shift_s[64];
  __shared__ float red_s[128];

  const int tid = threadIdx.x;
  const int lane = tid & 63;
  const int wave = tid >> 6;
  const int nn = lane & 15;
  const int kq = lane >> 4;

  if (tid < 64) {
    float sc, sh;
    bn_coeff(inStats, inG, inBe, invM_in, tid, sc, sh);
    scale_s[tid] = sc;
    shift_s[tid] = sh;
  }
#pragma unroll
  for (int i = 0; i < 16; ++i) {
    int idx = i * 256 + tid;
    int k = idx >> 6, n = idx & 63;
    Wt_s[n * 72 + k] = f2b(W[idx]);
  }
  __syncthreads();

  s16x8 bfrag[4][2];
#pragma unroll
  for (int nt = 0; nt < 4; ++nt)
#pragma unroll
    for (int kc = 0; kc < 2; ++kc)
      bfrag[nt][kc] = *(const s16x8*)&Wt_s[(nt * 16 + nn) * 72 + kc * 32 + kq * 8];

  float scf[2][8], shf[2][8];
#pragma unroll
  for (int kc = 0; kc < 2; ++kc) {
    int k0 = kc * 32 + kq * 8;
    float4 a = *(const float4*)&scale_s[k0];
    float4 b = *(const float4*)&scale_s[k0 + 4];
    float4 c = *(const float4*)&shift_s[k0];
    float4 d = *(const float4*)&shift_s[k0 + 4];
    scf[kc][0] = a.x; scf[kc][1] = a.y; scf[kc][2] = a.z; scf[kc][3] = a.w;
    scf[kc][4] = b.x; scf[kc][5] = b.y; scf[kc][6] = b.z; scf[kc][7] = b.w;
    shf[kc][0] = c.x; shf[kc][1] = c.y; shf[kc][2] = c.z; shf[kc][3] = c.w;
    shf[kc][4] = d.x; shf[kc][5] = d.y; shf[kc][6] = d.z; shf[kc][7] = d.w;
  }

  const int rbase = blockIdx.x * 256 + wave * 64;

  f32x4 acc[4][4];
#pragma unroll
  for (int rt = 0; rt < 4; ++rt)
#pragma unroll
    for (int nt = 0; nt < 4; ++nt) acc[rt][nt] = (f32x4){0.f, 0.f, 0.f, 0.f};

  uint4 raw[4][2];
#pragma unroll
  for (int rt = 0; rt < 4; ++rt) {
    int row = rbase + rt * 16 + nn;
    int rowc = row < M ? row : M - 1;
#pragma unroll
    for (int kc = 0; kc < 2; ++kc)
      raw[rt][kc] = *(const uint4*)&A0[(size_t)rowc * 64 + kc * 32 + kq * 8];
  }

#pragma unroll
  for (int rt = 0; rt < 4; ++rt) {
#pragma unroll
    for (int kc = 0; kc < 2; ++kc) {
      unsigned wbits[4] = {raw[rt][kc].x, raw[rt][kc].y, raw[rt][kc].z, raw[rt][kc].w};
      s16x8 af;
#pragma unroll
      for (int d = 0; d < 4; ++d) {
        union { unsigned u; float f; } lo, hi;
        lo.u = (wbits[d] & 0xffffu) << 16;
        hi.u = wbits[d] & 0xffff0000u;
        int j0 = d * 2, j1 = d * 2 + 1;
        af[j0] = (short)f2b(fmaxf(fmaf(scf[kc][j0], lo.f, shf[kc][j0]), 0.f));
        af[j1] = (short)f2b(fmaxf(fmaf(scf[kc][j1], hi.f, shf[kc][j1]), 0.f));
      }
#pragma unroll
      for (int nt = 0; nt < 4; ++nt)
        acc[rt][nt] = __builtin_amdgcn_mfma_f32_16x16x32_bf16(
            af, bfrag[nt][kc], acc[rt][nt], 0, 0, 0);
    }
  }

  float bcol[4];
#pragma unroll
  for (int nt = 0; nt < 4; ++nt) bcol[nt] = bias[nt * 16 + nn];

  float s[4] = {0.f, 0.f, 0.f, 0.f};
  float s2[4] = {0.f, 0.f, 0.f, 0.f};
#pragma unroll
  for (int rt = 0; rt < 4; ++rt)
#pragma unroll
    for (int nt = 0; nt < 4; ++nt) {
      int col = nt * 16 + nn;
#pragma unroll
      for (int reg = 0; reg < 4; ++reg) {
        int row = rbase + rt * 16 + kq * 4 + reg;
        if (row < M) {
          float y = acc[rt][nt][reg] + bcol[nt];
          outp[(size_t)row * 64 + col] = f2b(y);
          s[nt] += y; s2[nt] += y * y;
        }
      }
    }
#pragma unroll
  for (int nt = 0; nt < 4; ++nt) {
    s[nt] += __shfl_xor(s[nt], 16, 64);
    s[nt] += __shfl_xor(s[nt], 32, 64);
    s2[nt] += __shfl_xor(s2[nt], 16, 64);
    s2[nt] += __shfl_xor(s2[nt], 32, 64);
  }
  if (tid < 128) red_s[tid] = 0.f;
  __syncthreads();
  if (lane < 16) {
#pragma unroll
    for (int nt = 0; nt < 4; ++nt) {
      atomicAdd(&red_s[nt * 16 + nn], s[nt]);
      atomicAdd(&red_s[64 + nt * 16 + nn], s2[nt]);
    }
  }
  __syncthreads();
  if (tid < 128)
    atomicAdd(&outStats[(blockIdx.x & (NSHARD - 1)) * 128 + tid], red_s[tid]);
}

// ---------------------------------------------------------------------------
// gemm_concat_mfma: u1 = [h(fp32)|aggr(bf16)] @ W(128x64) + b (bf16 out)
// ---------------------------------------------------------------------------
__global__ __launch_bounds__(256) void gemm_concat_mfma(
    const float* __restrict__ A0,            // h fp32
    const unsigned short* __restrict__ A1b,  // aggr bf16
    const float* __restrict__ W,             // 128 x 64
    const float* __restrict__ bias,
    unsigned short* __restrict__ outp,       // u1 bf16
    float* __restrict__ outStats,
    int M)
{
  __shared__ __align__(16) unsigned short Wt_s[64 * 136];
  __shared__ float red_s[128];

  const int tid = threadIdx.x;
  const int lane = tid & 63;
  const int wave = tid >> 6;
  const int nn = lane & 15;
  const int kq = lane >> 4;

#pragma unroll
  for (int i = 0; i < 32; ++i) {
    int idx = i * 256 + tid;          // 8192
    int k = idx >> 6, n = idx & 63;
    Wt_s[n * 136 + k] = f2b(W[idx]);
  }
  __syncthreads();

  s16x8 bfrag[4][4];  // [nt][kc]
#pragma unroll
  for (int nt = 0; nt < 4; ++nt)
#pragma unroll
    for (int kc = 0; kc < 4; ++kc) {
      const unsigned short* p = &Wt_s[(nt * 16 + nn) * 136 + kc * 32 + kq * 8];
#pragma unroll
      for (int j = 0; j < 8; ++j) bfrag[nt][kc][j] = (short)p[j];
    }

  const int rbase = blockIdx.x * 128 + wave * 32;

  f32x4 acc[2][4];
#pragma unroll
  for (int rt = 0; rt < 2; ++rt)
#pragma unroll
    for (int nt = 0; nt < 4; ++nt) acc[rt][nt] = (f32x4){0.f, 0.f, 0.f, 0.f};

#pragma unroll
  for (int rt = 0; rt < 2; ++rt) {
    int row = rbase + rt * 16 + nn;
    int rowc = row < M ? row : M - 1;
#pragma unroll
    for (int kc = 0; kc < 4; ++kc) {
      s16x8 af;
      if (kc < 2) {
        af = frag_from_f32(&A0[(size_t)rowc * 64 + kc * 32 + kq * 8]);
      } else {
        af = *(const s16x8*)&A1b[(size_t)rowc * 64 + (kc - 2) * 32 + kq * 8];
      }
#pragma unroll
      for (int nt = 0; nt < 4; ++nt)
        acc[rt][nt] = __builtin_amdgcn_mfma_f32_16x16x32_bf16(
            af, bfrag[nt][kc], acc[rt][nt], 0, 0, 0);
    }
  }

  float bcol[4];
#pragma unroll
  for (int nt = 0; nt < 4; ++nt) bcol[nt] = bias[nt * 16 + nn];

  float s[4] = {0.f, 0.f, 0.f, 0.f};
  float s2[4] = {0.f, 0.f, 0.f, 0.f};
#pragma unroll
  for (int rt = 0; rt < 2; ++rt)
#pragma unroll
    for (int nt = 0; nt < 4; ++nt) {
      int col = nt * 16 + nn;
#pragma unroll
      for (int reg = 0; reg < 4; ++reg) {
        int row = rbase + rt * 16 + kq * 4 + reg;
        if (row < M) {
          float y = acc[rt][nt][reg] + bcol[nt];
          outp[(size_t)row * 64 + col] = f2b(y);
          s[nt] += y; s2[nt] += y * y;
        }
      }
    }
#pragma unroll
  for (int nt = 0; nt < 4; ++nt) {
    s[nt] += __shfl_xor(s[nt], 16, 64);
    s[nt] += __shfl_xor(s[nt], 32, 64);
    s2[nt] += __shfl_xor(s2[nt], 16, 64);
    s2[nt] += __shfl_xor(s2[nt], 32, 64);
  }
  if (tid < 128) red_s[tid] = 0.f;
  __syncthreads();
  if (lane < 16) {
#pragma unroll
    for (int nt = 0; nt < 4; ++nt) {
      atomicAdd(&red_s[nt * 16 + nn], s[nt]);
      atomicAdd(&red_s[64 + nt * 16 + nn], s2[nt]);
    }
  }
  __syncthreads();
  if (tid < 128)
    atomicAdd(&outStats[(blockIdx.x & (NSHARD - 1)) * 128 + tid], red_s[tid]);
}

// ---------------------------------------------------------------------------
// aggregate (wide loads): lane = (4 channels)x(row-quad). One uint2 load
// covers 4 full CSR rows per wave instruction (512B). ReLU per element,
// per-lane partials, xor-shuffle(16,32) reduce, 8B stores.
// ---------------------------------------------------------------------------
__global__ __launch_bounds__(256) void aggregate_kernel(
    const unsigned short* __restrict__ t2, const int* __restrict__ rowptr,
    const float* __restrict__ stats, const float* __restrict__ g,
    const float* __restrict__ be, float invM,
    unsigned short* __restrict__ aggr)
{
  int node = (blockIdx.x * 256 + threadIdx.x) >> 6;
  int lane = threadIdx.x & 63;
  if (node >= NN) return;
  const int c4 = (lane & 15) * 4;   // this lane's 4 channels
  const int rq = lane >> 4;         // row offset within quad (0..3)

  float sc[4], sh[4];
#pragma unroll
  for (int j = 0; j < 4; ++j)
    bn_coeff(stats, g, be, invM, c4 + j, sc[j], sh[j]);

  int lo = rowptr[node], hi = rowptr[node + 1];
  float acc[4] = {0.f, 0.f, 0.f, 0.f};

  for (int i = lo; i < hi; i += 8) {
    int r0 = i + rq;
    int r1 = i + 4 + rq;
    bool h0 = r0 < hi, h1 = r1 < hi;
    uint2 v0 = make_uint2(0u, 0u), v1 = make_uint2(0u, 0u);
    if (h0) v0 = *(const uint2*)&t2[(size_t)r0 * 64 + c4];
    if (h1) v1 = *(const uint2*)&t2[(size_t)r1 * 64 + c4];
    if (h0) {
      const unsigned w[2] = {v0.x, v0.y};
#pragma unroll
      for (int d = 0; d < 2; ++d) {
        union { unsigned u; float f; } a0, a1;
        a0.u = (w[d] & 0xffffu) << 16;
        a1.u = w[d] & 0xffff0000u;
        acc[d * 2] += fmaxf(fmaf(sc[d * 2], a0.f, sh[d * 2]), 0.f);
        acc[d * 2 + 1] += fmaxf(fmaf(sc[d * 2 + 1], a1.f, sh[d * 2 + 1]), 0.f);
      }
    }
    if (h1) {
      const unsigned w[2] = {v1.x, v1.y};
#pragma unroll
      for (int d = 0; d < 2; ++d) {
        union { unsigned u; float f; } a0, a1;
        a0.u = (w[d] & 0xffffu) << 16;
        a1.u = w[d] & 0xffff0000u;
        acc[d * 2] += fmaxf(fmaf(sc[d * 2], a0.f, sh[d * 2]), 0.f);
        acc[d * 2 + 1] += fmaxf(fmaf(sc[d * 2 + 1], a1.f, sh[d * 2 + 1]), 0.f);
      }
    }
  }
  // reduce across the 4 row-quads (lanes differing in bits 4,5)
#pragma unroll
  for (int j = 0; j < 4; ++j) {
    acc[j] += __shfl_xor(acc[j], 16, 64);
    acc[j] += __shfl_xor(acc[j], 32, 64);
  }
  if (rq == 0) {
    ushort4 o;
    o.x = f2b(acc[0]); o.y = f2b(acc[1]);
    o.z = f2b(acc[2]); o.w = f2b(acc[3]);
    *(ushort4*)&aggr[(size_t)node * 64 + c4] = o;
  }
}

// ---------------------------------------------------------------------------
// residual: h += relu(bn(u2_bf16))
// ---------------------------------------------------------------------------
__global__ __launch_bounds__(256) void residual_kernel(
    const unsigned short* __restrict__ u2, const float* __restrict__ stats,
    const float* __restrict__ g, const float* __restrict__ be,
    float invM, float* __restrict__ h)
{
  int gid = blockIdx.x * 256 + threadIdx.x;
  if (gid >= NN * 16) return;
  int c = (gid & 15) * 4;
  ushort4 v4 = *(const ushort4*)&u2[(size_t)gid * 4];
  float4 hv = *(const float4*)&h[(size_t)gid * 4];
  const unsigned short vu[4] = {v4.x, v4.y, v4.z, v4.w};
  float* hp = (float*)&hv;
#pragma unroll
  for (int j = 0; j < 4; ++j) {
    float sc, sh;
    bn_coeff(stats, g, be, invM, c + j, sc, sh);
    hp[j] += fmaxf(fmaf(sc, b2f(vu[j]), sh), 0.f);
  }
  *(float4*)&h[(size_t)gid * 4] = hv;
}

// ---------------------------------------------------------------------------
// pool: partial per-graph column sums, then tiny final with prediction head
// ---------------------------------------------------------------------------
constexpr int POOL_NPB = 128;  // nodes per block

__global__ __launch_bounds__(256) void pool_partial(
    const float* __restrict__ h, const int* __restrict__ batch,
    float* __restrict__ sums)  // NG x 64
{
  int lane = threadIdx.x & 63;
  int wave = threadIdx.x >> 6;
  int base = blockIdx.x * POOL_NPB;
  float acc = 0.f;
  int gcur = -1;
  for (int i = wave; i < POOL_NPB; i += 4) {
    int n = base + i;
    if (n >= NN) break;
    int g = batch[n];
    if (g != gcur) {
      if (gcur >= 0) atomicAdd(&sums[gcur * 64 + lane], acc);
      gcur = g;
      acc = 0.f;
    }
    acc += h[(size_t)n * 64 + lane];
  }
  if (gcur >= 0) atomicAdd(&sums[gcur * 64 + lane], acc);
}

DEV int lower_bound_i(const int* __restrict__ a, int n, int v) {
  int lo = 0, hi = n;
  while (lo < hi) {
    int m = (lo + hi) >> 1;
    if (a[m] < v) lo = m + 1; else hi = m;
  }
  return lo;
}

__global__ __launch_bounds__(64) void pool_final(
    const float* __restrict__ sums, const int* __restrict__ batch,
    const float* __restrict__ predW, const float* __restrict__ predB,
    float* __restrict__ out)
{
  int g = blockIdx.x;
  int lane = threadIdx.x;
  int lo = lower_bound_i(batch, NN, g);
  int hi = lower_bound_i(batch, NN, g + 1);
  float cnt = fmaxf((float)(hi - lo), 1.0f);
  float p = sums[g * 64 + lane] / cnt * predW[lane];
#pragma unroll
  for (int off = 32; off > 0; off >>= 1) p += __shfl_down(p, off, 64);
  if (lane == 0) out[g] = p + predB[0];
}

// ---------------------------------------------------------------------------
extern "C" void kernel_launch(void* const* d_in, const int* in_sizes, int n_in,
                              void* d_out, int out_size, void* d_ws, size_t ws_size,
                              hipStream_t stream)
{
  (void)in_sizes; (void)n_in; (void)out_size; (void)ws_size;

  const float* x        = (const float*)d_in[0];
  const float* edge_attr= (const float*)d_in[1];
  const int*   eidx     = (const int*)d_in[2];
  const int*   batch    = (const int*)d_in[3];
  const float* linW     = (const float*)d_in[4];
  const float* linB     = (const float*)d_in[5];
  const float* msgW1    = (const float*)d_in[6];
  const float* msgB1    = (const float*)d_in[7];
  const float* msgG1    = (const float*)d_in[8];
  const float* msgBe1   = (const float*)d_in[9];
  const float* msgW2    = (const float*)d_in[10];
  const float* msgB2    = (const float*)d_in[11];
  const float* msgG2    = (const float*)d_in[12];
  const float* msgBe2   = (const float*)d_in[13];
  const float* updW1    = (const float*)d_in[14];
  const float* updB1    = (const float*)d_in[15];
  const float* updG1    = (const float*)d_in[16];
  const float* updBe1   = (const float*)d_in[17];
  const float* updW2    = (const float*)d_in[18];
  const float* updB2    = (const float*)d_in[19];
  const float* updG2    = (const float*)d_in[20];
  const float* updBe2   = (const float*)d_in[21];
  const float* predW    = (const float*)d_in[22];
  const float* predB    = (const float*)d_in[23];

  const int* srcI = eidx;        // edge_index[0] = source
  const int* dstI = eidx + NE;   // edge_index[1] = target

  char* p = (char*)d_ws;
  float* h  = (float*)p;            p += (size_t)NN * 64 * 4;
  unsigned short* t1 = (unsigned short*)p; p += (size_t)NE * 64 * 2;
  unsigned short* aggr = (unsigned short*)p; p += (size_t)NN * 64 * 2;
  unsigned short* u1 = (unsigned short*)p;   p += (size_t)NN * 64 * 2;
  unsigned short* Hd = (unsigned short*)p;   p += (size_t)NN * 64 * 2;
  unsigned short* Hs = (unsigned short*)p;   p += (size_t)NN * 64 * 2;
  float* stats = (float*)p;         p += 16 * STB * 4;
  float* sums = (float*)p;          p += NG * 64 * 4;
  int* deg = (int*)p;               p += (size_t)NN * 4;
  int* cursor = (int*)p;            p += (size_t)NN * 4;
  int* rowptr = (int*)p;            p += (size_t)(NN + 1) * 4;
  int* srcP = (int*)p;              p += (size_t)NE * 4;
  int* dstP = (int*)p;              p += (size_t)NE * 4;
  float* eaP = (float*)p;           p += (size_t)NE * 4 * 4;
  int* blockSums = (int*)p;         p += 256 * 4;
  int* blockOffs = (int*)p;         p += 256 * 4;

  hipMemsetAsync(stats, 0, (16 * STB + NG * 64) * sizeof(float), stream);
  hipMemsetAsync(deg, 0, NN * sizeof(int), stream);

  hist_kernel<<<(NE + 255) / 256, 256, 0, stream>>>(dstI, deg);
  scan_pass1<<<SCAN_BLOCKS, 256, 0, stream>>>(deg, blockSums);
  scan_pass2<<<1, 256, 0, stream>>>(blockSums, blockOffs);
  scan_pass3<<<SCAN_BLOCKS, 256, 0, stream>>>(deg, blockOffs, rowptr, cursor);
  fill_permute_kernel<<<(NE + 255) / 256, 256, 0, stream>>>(
      srcI, dstI, edge_attr, cursor, srcP, dstP, eaP);

  lin_in_kernel<<<(NN * 64 + 255) / 256, 256, 0, stream>>>(x, linW, linB, h);

  const float invE = 1.0f / (float)NE;
  const float invN = 1.0f / (float)NN;
  const int NB128 = (NN + 127) / 128;         // 391
  const int NB256 = (NN + 255) / 256;         // 196
  const int EB256 = (NE + 255) / 256;         // 1563

  for (int l = 0; l < 4; ++l) {
    float* st0 = stats + (l * 4 + 0) * STB;
    float* st1 = stats + (l * 4 + 1) * STB;
    float* st2 = stats + (l * 4 + 2) * STB;
    float* st3 = stats + (l * 4 + 3) * STB;
    const float* W1 = msgW1 + (size_t)l * 132 * 64;

    // Hd = h @ W1[0:64], Hs = h @ W1[64:128]  (bf16 out, MFMA)
    gemm_dual_mfma<<<NB128, 256, 0, stream>>>(h, W1, Hd, Hs);

    // t1[p] = Hd[dstP] + Hs[srcP] + eaP@W1[128:132] + b1 (bf16) ; stats(st0)
    edge_combine<<<2048, 256, 0, stream>>>(
        Hd, Hs, eaP, srcP, dstP, W1 + 128 * 64, msgB1 + l * 64,
        t1, st0);

    // t1 = relu(bn(t1)) @ msgW2 + b2 (bf16, in-place, MFMA) ; stats(st1)
    gemm64_bn_mfma<<<EB256, 256, 0, stream>>>(
        t1, msgW2 + (size_t)l * 64 * 64, msgB2 + l * 64,
        st0, msgG1 + l * 64, msgBe1 + l * 64, invE,
        t1, st1, NE);

    // aggr[n] = sum relu(bn(t2)) over CSR rows (wide sequential stream)
    aggregate_kernel<<<(NN * 64 + 255) / 256, 256, 0, stream>>>(
        t1, rowptr, st1, msgG2 + l * 64, msgBe2 + l * 64, invE, aggr);

    // u1 = [h|aggr] @ updW1 + b1 (MFMA, bf16 out) ; stats(st2)
    gemm_concat_mfma<<<NB128, 256, 0, stream>>>(
        h, aggr, updW1 + (size_t)l * 128 * 64, updB1 + l * 64,
        u1, st2, NN);

    // u1 = relu(bn(u1)) @ updW2 + b2 (bf16, in-place, MFMA) ; stats(st3)
    gemm64_bn_mfma<<<NB256, 256, 0, stream>>>(
        u1, updW2 + (size_t)l * 64 * 64, updB2 + l * 64,
        st2, updG1 + l * 64, updBe1 + l * 64, invN,
        u1, st3, NN);

    // h += relu(bn(u1))
    residual_kernel<<<(NN * 16 + 255) / 256, 256, 0, stream>>>(
        u1, st3, updG2 + l * 64, updBe2 + l * 64, invN, h);
  }

  pool_partial<<<(NN + POOL_NPB - 1) / POOL_NPB, 256, 0, stream>>>(h, batch, sums);
  pool_final<<<NG, 64, 0, stream>>>(sums, batch, predW, predB, (float*)d_out);
}

// Round 11
// 683.312 us; speedup vs baseline: 1.4384x; 1.1462x over previous
//
#include <hip/hip_runtime.h>

#define DEV __device__ __forceinline__

constexpr int NN = 50000;   // nodes
constexpr int NE = 400000;  // edges
constexpr int NG = 32;      // graphs
constexpr float EPSV = 1e-5f;
constexpr int SCAN_BLOCKS = 196;  // 196*256 = 50176 >= NN
constexpr int NSHARD = 8;         // stats shards (atomic-contention relief)
constexpr int STB = NSHARD * 128; // floats per BN-stats instance

typedef __attribute__((ext_vector_type(8))) short s16x8;
typedef __attribute__((ext_vector_type(4))) float f32x4;

DEV unsigned short f2b(float f) {  // fp32 -> bf16 RNE (finite inputs)
  union { float f; unsigned u; } x; x.f = f;
  unsigned r = x.u + 0x7fffu + ((x.u >> 16) & 1u);
  return (unsigned short)(r >> 16);
}
DEV float b2f(unsigned short u) {
  union { unsigned u; float f; } x; x.u = ((unsigned)u) << 16; return x.f;
}

DEV s16x8 frag_from_f32(const float* p) {
  const float4 v0 = *(const float4*)p;
  const float4 v1 = *(const float4*)(p + 4);
  s16x8 af;
  af[0] = (short)f2b(v0.x); af[1] = (short)f2b(v0.y);
  af[2] = (short)f2b(v0.z); af[3] = (short)f2b(v0.w);
  af[4] = (short)f2b(v1.x); af[5] = (short)f2b(v1.y);
  af[6] = (short)f2b(v1.z); af[7] = (short)f2b(v1.w);
  return af;
}

// sum the NSHARD shards of a stats instance and produce scale/shift for ch c.
// Call once per BLOCK (tid<64) and stage in LDS — never per thread.
DEV void bn_coeff(const float* __restrict__ st, const float* __restrict__ g,
                  const float* __restrict__ be, float invM, int c,
                  float& sc, float& sh) {
  float s = 0.f, s2 = 0.f;
#pragma unroll
  for (int k = 0; k < NSHARD; ++k) {
    s += st[k * 128 + c];
    s2 += st[k * 128 + 64 + c];
  }
  float mean = s * invM;
  float var = s2 * invM - mean * mean;
  sc = g[c] * rsqrtf(var + EPSV);
  sh = be[c] - mean * sc;
}

// ---------------------------------------------------------------------------
// lin_in: h = x @ W(11x64) + b
// ---------------------------------------------------------------------------
__global__ __launch_bounds__(256) void lin_in_kernel(
    const float* __restrict__ x, const float* __restrict__ W,
    const float* __restrict__ b, float* __restrict__ h)
{
  int gid = blockIdx.x * 256 + threadIdx.x;
  if (gid >= NN * 64) return;
  int n = gid >> 6, c = gid & 63;
  float acc = b[c];
#pragma unroll
  for (int k = 0; k < 11; ++k)
    acc = fmaf(x[n * 11 + k], W[k * 64 + c], acc);
  h[gid] = acc;
}

// ---------------------------------------------------------------------------
// CSR build: histogram -> hierarchical exclusive scan -> permuting fill.
// ---------------------------------------------------------------------------
__global__ __launch_bounds__(256) void hist_kernel(
    const int* __restrict__ dstI, int* __restrict__ deg)
{
  int e = blockIdx.x * 256 + threadIdx.x;
  if (e < NE) atomicAdd(&deg[dstI[e]], 1);
}

__global__ __launch_bounds__(256) void scan_pass1(
    const int* __restrict__ deg, int* __restrict__ blockSums)
{
  __shared__ int red[4];
  int tid = threadIdx.x;
  int idx = blockIdx.x * 256 + tid;
  int v = (idx < NN) ? deg[idx] : 0;
#pragma unroll
  for (int off = 32; off > 0; off >>= 1) v += __shfl_down(v, off, 64);
  if ((tid & 63) == 0) red[tid >> 6] = v;
  __syncthreads();
  if (tid == 0) blockSums[blockIdx.x] = red[0] + red[1] + red[2] + red[3];
}

__global__ __launch_bounds__(256) void scan_pass2(
    const int* __restrict__ blockSums, int* __restrict__ blockOffs)
{
  __shared__ int part[256];
  int tid = threadIdx.x;
  int v = (tid < SCAN_BLOCKS) ? blockSums[tid] : 0;
  part[tid] = v;
  __syncthreads();
  for (int off = 1; off < 256; off <<= 1) {
    int t = 0;
    if (tid >= off) t = part[tid - off];
    __syncthreads();
    if (tid >= off) part[tid] += t;
    __syncthreads();
  }
  blockOffs[tid] = (tid == 0) ? 0 : part[tid - 1];
}

__global__ __launch_bounds__(256) void scan_pass3(
    const int* __restrict__ deg, const int* __restrict__ blockOffs,
    int* __restrict__ rowptr, int* __restrict__ cursor)
{
  __shared__ int part[256];
  int tid = threadIdx.x;
  int idx = blockIdx.x * 256 + tid;
  int v = (idx < NN) ? deg[idx] : 0;
  part[tid] = v;
  __syncthreads();
  for (int off = 1; off < 256; off <<= 1) {
    int t = 0;
    if (tid >= off) t = part[tid - off];
    __syncthreads();
    if (tid >= off) part[tid] += t;
    __syncthreads();
  }
  int excl = (tid == 0) ? 0 : part[tid - 1];
  int val = blockOffs[blockIdx.x] + excl;
  if (idx < NN) { rowptr[idx] = val; cursor[idx] = val; }
  if (idx == 0) rowptr[NN] = NE;
}

__global__ __launch_bounds__(256) void fill_permute_kernel(
    const int* __restrict__ srcI, const int* __restrict__ dstI,
    const float* __restrict__ ea, int* __restrict__ cursor,
    int* __restrict__ srcP, int* __restrict__ dstP,
    float* __restrict__ eaP)
{
  int e = blockIdx.x * 256 + threadIdx.x;
  if (e < NE) {
    int d = dstI[e];
    int pos = atomicAdd(&cursor[d], 1);
    srcP[pos] = srcI[e];
    dstP[pos] = d;
    *(float4*)&eaP[(size_t)pos * 4] = *(const float4*)&ea[(size_t)e * 4];
  }
}

// ---------------------------------------------------------------------------
// gemm_dual_mfma: Hd = h @ W[0:64], Hs = h @ W[64:128] (bf16 out, MFMA)
// ---------------------------------------------------------------------------
__global__ __launch_bounds__(256) void gemm_dual_mfma(
    const float* __restrict__ h, const float* __restrict__ W, // 132x64
    unsigned short* __restrict__ Hd, unsigned short* __restrict__ Hs)
{
  __shared__ __align__(16) unsigned short Wt_s[2 * 64 * 72];  // [half][n][k]

  const int tid = threadIdx.x;
  const int lane = tid & 63;
  const int wave = tid >> 6;
  const int nn = lane & 15;
  const int kq = lane >> 4;

#pragma unroll
  for (int i = 0; i < 32; ++i) {
    int idx = i * 256 + tid;          // 8192 = 2*64*64
    int half = idx >> 12;
    int rem = idx & 4095;
    int k = rem >> 6, n = rem & 63;
    Wt_s[half * 4608 + n * 72 + k] = f2b(W[idx]);
  }
  __syncthreads();

  s16x8 bfrag[2][4][2];  // [out][nt][kc]
#pragma unroll
  for (int o = 0; o < 2; ++o)
#pragma unroll
    for (int nt = 0; nt < 4; ++nt)
#pragma unroll
      for (int kc = 0; kc < 2; ++kc) {
        const unsigned short* p =
            &Wt_s[o * 4608 + (nt * 16 + nn) * 72 + kc * 32 + kq * 8];
#pragma unroll
        for (int j = 0; j < 8; ++j) bfrag[o][nt][kc][j] = (short)p[j];
      }

  const int rbase = blockIdx.x * 128 + wave * 32;

  f32x4 acc[2][2][4];  // [out][rt][nt]
#pragma unroll
  for (int o = 0; o < 2; ++o)
#pragma unroll
    for (int rt = 0; rt < 2; ++rt)
#pragma unroll
      for (int nt = 0; nt < 4; ++nt) acc[o][rt][nt] = (f32x4){0.f, 0.f, 0.f, 0.f};

#pragma unroll
  for (int rt = 0; rt < 2; ++rt) {
    int row = rbase + rt * 16 + nn;
    int rowc = row < NN ? row : NN - 1;
#pragma unroll
    for (int kc = 0; kc < 2; ++kc) {
      s16x8 af = frag_from_f32(&h[(size_t)rowc * 64 + kc * 32 + kq * 8]);
#pragma unroll
      for (int o = 0; o < 2; ++o)
#pragma unroll
        for (int nt = 0; nt < 4; ++nt)
          acc[o][rt][nt] = __builtin_amdgcn_mfma_f32_16x16x32_bf16(
              af, bfrag[o][nt][kc], acc[o][rt][nt], 0, 0, 0);
    }
  }

#pragma unroll
  for (int rt = 0; rt < 2; ++rt)
#pragma unroll
    for (int nt = 0; nt < 4; ++nt) {
      int col = nt * 16 + nn;
#pragma unroll
      for (int reg = 0; reg < 4; ++reg) {
        int row = rbase + rt * 16 + kq * 4 + reg;
        if (row < NN) {
          Hd[(size_t)row * 64 + col] = f2b(acc[0][rt][nt][reg]);
          Hs[(size_t)row * 64 + col] = f2b(acc[1][rt][nt][reg]);
        }
      }
    }
}

// ---------------------------------------------------------------------------
// edge_combine: t1[p] = Hd[dstP[p]] + Hs[srcP[p]] + eaP[p]@Wb + b (bf16 out)
// 8 lanes/edge, 16B ops, 2x grid-stride unroll; sharded stats.
// ---------------------------------------------------------------------------
__global__ __launch_bounds__(256) void edge_combine(
    const unsigned short* __restrict__ Hd, const unsigned short* __restrict__ Hs,
    const float* __restrict__ eaP, const int* __restrict__ srcP,
    const int* __restrict__ dstP, const float* __restrict__ Wb, // 4x64
    const float* __restrict__ bias, unsigned short* __restrict__ t1,
    float* __restrict__ outStats)
{
  __shared__ float red_s[128];
  const int tid = threadIdx.x;
  const int c0 = (tid & 7) * 8;
  float bv[8], w0[8], w1[8], w2[8], w3[8];
#pragma unroll
  for (int j = 0; j < 8; ++j) {
    bv[j] = bias[c0 + j];
    w0[j] = Wb[0 * 64 + c0 + j];
    w1[j] = Wb[1 * 64 + c0 + j];
    w2[j] = Wb[2 * 64 + c0 + j];
    w3[j] = Wb[3 * 64 + c0 + j];
  }

  float s[8], s2[8];
#pragma unroll
  for (int j = 0; j < 8; ++j) { s[j] = 0.f; s2[j] = 0.f; }

  const int e0 = (blockIdx.x * 256 + tid) >> 3;
  const int estep = (gridDim.x * 256) >> 3;

  for (int e = e0; e < NE; e += 2 * estep) {
    int eb = e + estep;
    bool hasB = eb < NE;
    int siA = srcP[e], diA = dstP[e];
    float4 avA = *(const float4*)&eaP[(size_t)e * 4];
    uint4 hdA = *(const uint4*)&Hd[(size_t)diA * 64 + c0];
    uint4 hsA = *(const uint4*)&Hs[(size_t)siA * 64 + c0];
    int ebc = hasB ? eb : e;
    int siB = srcP[ebc], diB = dstP[ebc];
    float4 avB = *(const float4*)&eaP[(size_t)ebc * 4];
    uint4 hdB = *(const uint4*)&Hd[(size_t)diB * 64 + c0];
    uint4 hsB = *(const uint4*)&Hs[(size_t)siB * 64 + c0];

    {
      const unsigned hdw[4] = {hdA.x, hdA.y, hdA.z, hdA.w};
      const unsigned hsw[4] = {hsA.x, hsA.y, hsA.z, hsA.w};
      unsigned short ob[8];
#pragma unroll
      for (int d = 0; d < 4; ++d) {
        union { unsigned u; float f; } a0, a1, b0, b1;
        a0.u = (hdw[d] & 0xffffu) << 16; a1.u = hdw[d] & 0xffff0000u;
        b0.u = (hsw[d] & 0xffffu) << 16; b1.u = hsw[d] & 0xffff0000u;
        int j0 = d * 2, j1 = d * 2 + 1;
        float y0 = a0.f + b0.f + bv[j0] + avA.x * w0[j0] + avA.y * w1[j0] + avA.z * w2[j0] + avA.w * w3[j0];
        float y1 = a1.f + b1.f + bv[j1] + avA.x * w0[j1] + avA.y * w1[j1] + avA.z * w2[j1] + avA.w * w3[j1];
        ob[j0] = f2b(y0); ob[j1] = f2b(y1);
        s[j0] += y0; s2[j0] += y0 * y0;
        s[j1] += y1; s2[j1] += y1 * y1;
      }
      *(uint4*)&t1[(size_t)e * 64 + c0] = *(const uint4*)ob;
    }
    if (hasB) {
      const unsigned hdw[4] = {hdB.x, hdB.y, hdB.z, hdB.w};
      const unsigned hsw[4] = {hsB.x, hsB.y, hsB.z, hsB.w};
      unsigned short ob[8];
#pragma unroll
      for (int d = 0; d < 4; ++d) {
        union { unsigned u; float f; } a0, a1, b0, b1;
        a0.u = (hdw[d] & 0xffffu) << 16; a1.u = hdw[d] & 0xffff0000u;
        b0.u = (hsw[d] & 0xffffu) << 16; b1.u = hsw[d] & 0xffff0000u;
        int j0 = d * 2, j1 = d * 2 + 1;
        float y0 = a0.f + b0.f + bv[j0] + avB.x * w0[j0] + avB.y * w1[j0] + avB.z * w2[j0] + avB.w * w3[j0];
        float y1 = a1.f + b1.f + bv[j1] + avB.x * w0[j1] + avB.y * w1[j1] + avB.z * w2[j1] + avB.w * w3[j1];
        ob[j0] = f2b(y0); ob[j1] = f2b(y1);
        s[j0] += y0; s2[j0] += y0 * y0;
        s[j1] += y1; s2[j1] += y1 * y1;
      }
      *(uint4*)&t1[(size_t)eb * 64 + c0] = *(const uint4*)ob;
    }
  }
#pragma unroll
  for (int j = 0; j < 8; ++j) {
    s[j] += __shfl_xor(s[j], 8, 64);
    s[j] += __shfl_xor(s[j], 16, 64);
    s[j] += __shfl_xor(s[j], 32, 64);
    s2[j] += __shfl_xor(s2[j], 8, 64);
    s2[j] += __shfl_xor(s2[j], 16, 64);
    s2[j] += __shfl_xor(s2[j], 32, 64);
  }
  if (tid < 128) red_s[tid] = 0.f;
  __syncthreads();
  if ((tid & 63) < 8) {
#pragma unroll
    for (int j = 0; j < 8; ++j) {
      atomicAdd(&red_s[c0 + j], s[j]);
      atomicAdd(&red_s[64 + c0 + j], s2[j]);
    }
  }
  __syncthreads();
  if (tid < 128)
    atomicAdd(&outStats[(blockIdx.x & (NSHARD - 1)) * 128 + tid], red_s[tid]);
}

// ---------------------------------------------------------------------------
// gemm64_bn_mfma: out = relu(bn(A)) @ W + b — bf16 in/out, MFMA, in-place ok.
// 64 rows per wave (256-row block), 8 independent A-loads in flight/lane.
// Sharded stats in (summed once per block) and out (scattered).
// ---------------------------------------------------------------------------
__global__ __launch_bounds__(256) void gemm64_bn_mfma(
    const unsigned short* A0,         // bf16 M x 64 (may alias outp)
    const float* __restrict__ W,      // 64 x 64 fp32
    const float* __restrict__ bias,
    const float* __restrict__ inStats,
    const float* __restrict__ inG,
    const float* __restrict__ inBe,
    float invM_in,
    unsigned short* outp,             // bf16 M x 64
    float* __restrict__ outStats,
    int M)
{
  __shared__ __align__(16) unsigned short Wt_s[64 * 72];
  __shared__ float scale_s[64];
  __shared__ float shift_s[64];
  __shared__ float red_s[128];

  const int tid = threadIdx.x;
  const int lane = tid & 63;
  const int wave = tid >> 6;
  const int nn = lane & 15;
  const int kq = lane >> 4;

  if (tid < 64) {
    float sc, sh;
    bn_coeff(inStats, inG, inBe, invM_in, tid, sc, sh);
    scale_s[tid] = sc;
    shift_s[tid] = sh;
  }
#pragma unroll
  for (int i = 0; i < 16; ++i) {
    int idx = i * 256 + tid;
    int k = idx >> 6, n = idx & 63;
    Wt_s[n * 72 + k] = f2b(W[idx]);
  }
  __syncthreads();

  s16x8 bfrag[4][2];
#pragma unroll
  for (int nt = 0; nt < 4; ++nt)
#pragma unroll
    for (int kc = 0; kc < 2; ++kc)
      bfrag[nt][kc] = *(const s16x8*)&Wt_s[(nt * 16 + nn) * 72 + kc * 32 + kq * 8];

  float scf[2][8], shf[2][8];
#pragma unroll
  for (int kc = 0; kc < 2; ++kc) {
    int k0 = kc * 32 + kq * 8;
    float4 a = *(const float4*)&scale_s[k0];
    float4 b = *(const float4*)&scale_s[k0 + 4];
    float4 c = *(const float4*)&shift_s[k0];
    float4 d = *(const float4*)&shift_s[k0 + 4];
    scf[kc][0] = a.x; scf[kc][1] = a.y; scf[kc][2] = a.z; scf[kc][3] = a.w;
    scf[kc][4] = b.x; scf[kc][5] = b.y; scf[kc][6] = b.z; scf[kc][7] = b.w;
    shf[kc][0] = c.x; shf[kc][1] = c.y; shf[kc][2] = c.z; shf[kc][3] = c.w;
    shf[kc][4] = d.x; shf[kc][5] = d.y; shf[kc][6] = d.z; shf[kc][7] = d.w;
  }

  const int rbase = blockIdx.x * 256 + wave * 64;

  f32x4 acc[4][4];
#pragma unroll
  for (int rt = 0; rt < 4; ++rt)
#pragma unroll
    for (int nt = 0; nt < 4; ++nt) acc[rt][nt] = (f32x4){0.f, 0.f, 0.f, 0.f};

  uint4 raw[4][2];
#pragma unroll
  for (int rt = 0; rt < 4; ++rt) {
    int row = rbase + rt * 16 + nn;
    int rowc = row < M ? row : M - 1;
#pragma unroll
    for (int kc = 0; kc < 2; ++kc)
      raw[rt][kc] = *(const uint4*)&A0[(size_t)rowc * 64 + kc * 32 + kq * 8];
  }

#pragma unroll
  for (int rt = 0; rt < 4; ++rt) {
#pragma unroll
    for (int kc = 0; kc < 2; ++kc) {
      unsigned wbits[4] = {raw[rt][kc].x, raw[rt][kc].y, raw[rt][kc].z, raw[rt][kc].w};
      s16x8 af;
#pragma unroll
      for (int d = 0; d < 4; ++d) {
        union { unsigned u; float f; } lo, hi;
        lo.u = (wbits[d] & 0xffffu) << 16;
        hi.u = wbits[d] & 0xffff0000u;
        int j0 = d * 2, j1 = d * 2 + 1;
        af[j0] = (short)f2b(fmaxf(fmaf(scf[kc][j0], lo.f, shf[kc][j0]), 0.f));
        af[j1] = (short)f2b(fmaxf(fmaf(scf[kc][j1], hi.f, shf[kc][j1]), 0.f));
      }
#pragma unroll
      for (int nt = 0; nt < 4; ++nt)
        acc[rt][nt] = __builtin_amdgcn_mfma_f32_16x16x32_bf16(
            af, bfrag[nt][kc], acc[rt][nt], 0, 0, 0);
    }
  }

  float bcol[4];
#pragma unroll
  for (int nt = 0; nt < 4; ++nt) bcol[nt] = bias[nt * 16 + nn];

  float s[4] = {0.f, 0.f, 0.f, 0.f};
  float s2[4] = {0.f, 0.f, 0.f, 0.f};
#pragma unroll
  for (int rt = 0; rt < 4; ++rt)
#pragma unroll
    for (int nt = 0; nt < 4; ++nt) {
      int col = nt * 16 + nn;
#pragma unroll
      for (int reg = 0; reg < 4; ++reg) {
        int row = rbase + rt * 16 + kq * 4 + reg;
        if (row < M) {
          float y = acc[rt][nt][reg] + bcol[nt];
          outp[(size_t)row * 64 + col] = f2b(y);
          s[nt] += y; s2[nt] += y * y;
        }
      }
    }
#pragma unroll
  for (int nt = 0; nt < 4; ++nt) {
    s[nt] += __shfl_xor(s[nt], 16, 64);
    s[nt] += __shfl_xor(s[nt], 32, 64);
    s2[nt] += __shfl_xor(s2[nt], 16, 64);
    s2[nt] += __shfl_xor(s2[nt], 32, 64);
  }
  if (tid < 128) red_s[tid] = 0.f;
  __syncthreads();
  if (lane < 16) {
#pragma unroll
    for (int nt = 0; nt < 4; ++nt) {
      atomicAdd(&red_s[nt * 16 + nn], s[nt]);
      atomicAdd(&red_s[64 + nt * 16 + nn], s2[nt]);
    }
  }
  __syncthreads();
  if (tid < 128)
    atomicAdd(&outStats[(blockIdx.x & (NSHARD - 1)) * 128 + tid], red_s[tid]);
}

// ---------------------------------------------------------------------------
// gemm_concat_mfma: u1 = [h(fp32)|aggr(bf16)] @ W(128x64) + b (bf16 out)
// ---------------------------------------------------------------------------
__global__ __launch_bounds__(256) void gemm_concat_mfma(
    const float* __restrict__ A0,            // h fp32
    const unsigned short* __restrict__ A1b,  // aggr bf16
    const float* __restrict__ W,             // 128 x 64
    const float* __restrict__ bias,
    unsigned short* __restrict__ outp,       // u1 bf16
    float* __restrict__ outStats,
    int M)
{
  __shared__ __align__(16) unsigned short Wt_s[64 * 136];
  __shared__ float red_s[128];

  const int tid = threadIdx.x;
  const int lane = tid & 63;
  const int wave = tid >> 6;
  const int nn = lane & 15;
  const int kq = lane >> 4;

#pragma unroll
  for (int i = 0; i < 32; ++i) {
    int idx = i * 256 + tid;          // 8192
    int k = idx >> 6, n = idx & 63;
    Wt_s[n * 136 + k] = f2b(W[idx]);
  }
  __syncthreads();

  s16x8 bfrag[4][4];  // [nt][kc]
#pragma unroll
  for (int nt = 0; nt < 4; ++nt)
#pragma unroll
    for (int kc = 0; kc < 4; ++kc) {
      const unsigned short* p = &Wt_s[(nt * 16 + nn) * 136 + kc * 32 + kq * 8];
#pragma unroll
      for (int j = 0; j < 8; ++j) bfrag[nt][kc][j] = (short)p[j];
    }

  const int rbase = blockIdx.x * 128 + wave * 32;

  f32x4 acc[2][4];
#pragma unroll
  for (int rt = 0; rt < 2; ++rt)
#pragma unroll
    for (int nt = 0; nt < 4; ++nt) acc[rt][nt] = (f32x4){0.f, 0.f, 0.f, 0.f};

#pragma unroll
  for (int rt = 0; rt < 2; ++rt) {
    int row = rbase + rt * 16 + nn;
    int rowc = row < M ? row : M - 1;
#pragma unroll
    for (int kc = 0; kc < 4; ++kc) {
      s16x8 af;
      if (kc < 2) {
        af = frag_from_f32(&A0[(size_t)rowc * 64 + kc * 32 + kq * 8]);
      } else {
        af = *(const s16x8*)&A1b[(size_t)rowc * 64 + (kc - 2) * 32 + kq * 8];
      }
#pragma unroll
      for (int nt = 0; nt < 4; ++nt)
        acc[rt][nt] = __builtin_amdgcn_mfma_f32_16x16x32_bf16(
            af, bfrag[nt][kc], acc[rt][nt], 0, 0, 0);
    }
  }

  float bcol[4];
#pragma unroll
  for (int nt = 0; nt < 4; ++nt) bcol[nt] = bias[nt * 16 + nn];

  float s[4] = {0.f, 0.f, 0.f, 0.f};
  float s2[4] = {0.f, 0.f, 0.f, 0.f};
#pragma unroll
  for (int rt = 0; rt < 2; ++rt)
#pragma unroll
    for (int nt = 0; nt < 4; ++nt) {
      int col = nt * 16 + nn;
#pragma unroll
      for (int reg = 0; reg < 4; ++reg) {
        int row = rbase + rt * 16 + kq * 4 + reg;
        if (row < M) {
          float y = acc[rt][nt][reg] + bcol[nt];
          outp[(size_t)row * 64 + col] = f2b(y);
          s[nt] += y; s2[nt] += y * y;
        }
      }
    }
#pragma unroll
  for (int nt = 0; nt < 4; ++nt) {
    s[nt] += __shfl_xor(s[nt], 16, 64);
    s[nt] += __shfl_xor(s[nt], 32, 64);
    s2[nt] += __shfl_xor(s2[nt], 16, 64);
    s2[nt] += __shfl_xor(s2[nt], 32, 64);
  }
  if (tid < 128) red_s[tid] = 0.f;
  __syncthreads();
  if (lane < 16) {
#pragma unroll
    for (int nt = 0; nt < 4; ++nt) {
      atomicAdd(&red_s[nt * 16 + nn], s[nt]);
      atomicAdd(&red_s[64 + nt * 16 + nn], s2[nt]);
    }
  }
  __syncthreads();
  if (tid < 128)
    atomicAdd(&outStats[(blockIdx.x & (NSHARD - 1)) * 128 + tid], red_s[tid]);
}

// ---------------------------------------------------------------------------
// aggregate (wide): lane = (8 channels)x(row-octet). uint4 loads: 16B/lane,
// a wave covers 8 full CSR rows per load, 16 rows per iteration.
// BN coeffs staged in LDS once per block. xor-shuffle(8,16,32) reduce.
// ---------------------------------------------------------------------------
__global__ __launch_bounds__(256) void aggregate_kernel(
    const unsigned short* __restrict__ t2, const int* __restrict__ rowptr,
    const float* __restrict__ stats, const float* __restrict__ g,
    const float* __restrict__ be, float invM,
    unsigned short* __restrict__ aggr)
{
  __shared__ float sc_s[64], sh_s[64];
  const int tid = threadIdx.x;
  if (tid < 64) {
    float sc, sh;
    bn_coeff(stats, g, be, invM, tid, sc, sh);
    sc_s[tid] = sc;
    sh_s[tid] = sh;
  }
  __syncthreads();

  int node = (blockIdx.x * 256 + tid) >> 6;
  int lane = tid & 63;
  if (node >= NN) return;
  const int c8 = (lane & 7) * 8;    // this lane's 8 channels
  const int rq = lane >> 3;         // row offset within octet (0..7)

  float sc[8], sh[8];
#pragma unroll
  for (int j = 0; j < 8; ++j) {
    sc[j] = sc_s[c8 + j];
    sh[j] = sh_s[c8 + j];
  }

  int lo = rowptr[node], hi = rowptr[node + 1];
  float acc[8] = {0.f, 0.f, 0.f, 0.f, 0.f, 0.f, 0.f, 0.f};

  for (int i = lo; i < hi; i += 16) {
    int r0 = i + rq;
    int r1 = i + 8 + rq;
    bool h0 = r0 < hi, h1 = r1 < hi;
    uint4 v0 = make_uint4(0u, 0u, 0u, 0u), v1 = make_uint4(0u, 0u, 0u, 0u);
    if (h0) v0 = *(const uint4*)&t2[(size_t)r0 * 64 + c8];
    if (h1) v1 = *(const uint4*)&t2[(size_t)r1 * 64 + c8];
    if (h0) {
      const unsigned w[4] = {v0.x, v0.y, v0.z, v0.w};
#pragma unroll
      for (int d = 0; d < 4; ++d) {
        union { unsigned u; float f; } a0, a1;
        a0.u = (w[d] & 0xffffu) << 16;
        a1.u = w[d] & 0xffff0000u;
        acc[d * 2] += fmaxf(fmaf(sc[d * 2], a0.f, sh[d * 2]), 0.f);
        acc[d * 2 + 1] += fmaxf(fmaf(sc[d * 2 + 1], a1.f, sh[d * 2 + 1]), 0.f);
      }
    }
    if (h1) {
      const unsigned w[4] = {v1.x, v1.y, v1.z, v1.w};
#pragma unroll
      for (int d = 0; d < 4; ++d) {
        union { unsigned u; float f; } a0, a1;
        a0.u = (w[d] & 0xffffu) << 16;
        a1.u = w[d] & 0xffff0000u;
        acc[d * 2] += fmaxf(fmaf(sc[d * 2], a0.f, sh[d * 2]), 0.f);
        acc[d * 2 + 1] += fmaxf(fmaf(sc[d * 2 + 1], a1.f, sh[d * 2 + 1]), 0.f);
      }
    }
  }
  // reduce across the 8 row-octets (lanes differing in bits 3,4,5)
#pragma unroll
  for (int j = 0; j < 8; ++j) {
    acc[j] += __shfl_xor(acc[j], 8, 64);
    acc[j] += __shfl_xor(acc[j], 16, 64);
    acc[j] += __shfl_xor(acc[j], 32, 64);
  }
  if (rq == 0) {
    unsigned short o[8];
#pragma unroll
    for (int j = 0; j < 8; ++j) o[j] = f2b(acc[j]);
    *(uint4*)&aggr[(size_t)node * 64 + c8] = *(const uint4*)o;
  }
}

// ---------------------------------------------------------------------------
// residual: h += relu(bn(u2_bf16))   (BN coeffs staged in LDS per block)
// ---------------------------------------------------------------------------
__global__ __launch_bounds__(256) void residual_kernel(
    const unsigned short* __restrict__ u2, const float* __restrict__ stats,
    const float* __restrict__ g, const float* __restrict__ be,
    float invM, float* __restrict__ h)
{
  __shared__ float sc_s[64], sh_s[64];
  const int tid = threadIdx.x;
  if (tid < 64) {
    float sc, sh;
    bn_coeff(stats, g, be, invM, tid, sc, sh);
    sc_s[tid] = sc;
    sh_s[tid] = sh;
  }
  __syncthreads();

  int gid = blockIdx.x * 256 + tid;
  if (gid >= NN * 16) return;
  int c = (gid & 15) * 4;
  ushort4 v4 = *(const ushort4*)&u2[(size_t)gid * 4];
  float4 hv = *(const float4*)&h[(size_t)gid * 4];
  const unsigned short vu[4] = {v4.x, v4.y, v4.z, v4.w};
  float* hp = (float*)&hv;
#pragma unroll
  for (int j = 0; j < 4; ++j)
    hp[j] += fmaxf(fmaf(sc_s[c + j], b2f(vu[j]), sh_s[c + j]), 0.f);
  *(float4*)&h[(size_t)gid * 4] = hv;
}

// ---------------------------------------------------------------------------
// pool: partial per-graph column sums, then tiny final with prediction head
// ---------------------------------------------------------------------------
constexpr int POOL_NPB = 128;  // nodes per block

__global__ __launch_bounds__(256) void pool_partial(
    const float* __restrict__ h, const int* __restrict__ batch,
    float* __restrict__ sums)  // NG x 64
{
  int lane = threadIdx.x & 63;
  int wave = threadIdx.x >> 6;
  int base = blockIdx.x * POOL_NPB;
  float acc = 0.f;
  int gcur = -1;
  for (int i = wave; i < POOL_NPB; i += 4) {
    int n = base + i;
    if (n >= NN) break;
    int g = batch[n];
    if (g != gcur) {
      if (gcur >= 0) atomicAdd(&sums[gcur * 64 + lane], acc);
      gcur = g;
      acc = 0.f;
    }
    acc += h[(size_t)n * 64 + lane];
  }
  if (gcur >= 0) atomicAdd(&sums[gcur * 64 + lane], acc);
}

DEV int lower_bound_i(const int* __restrict__ a, int n, int v) {
  int lo = 0, hi = n;
  while (lo < hi) {
    int m = (lo + hi) >> 1;
    if (a[m] < v) lo = m + 1; else hi = m;
  }
  return lo;
}

__global__ __launch_bounds__(64) void pool_final(
    const float* __restrict__ sums, const int* __restrict__ batch,
    const float* __restrict__ predW, const float* __restrict__ predB,
    float* __restrict__ out)
{
  int g = blockIdx.x;
  int lane = threadIdx.x;
  int lo = lower_bound_i(batch, NN, g);
  int hi = lower_bound_i(batch, NN, g + 1);
  float cnt = fmaxf((float)(hi - lo), 1.0f);
  float p = sums[g * 64 + lane] / cnt * predW[lane];
#pragma unroll
  for (int off = 32; off > 0; off >>= 1) p += __shfl_down(p, off, 64);
  if (lane == 0) out[g] = p + predB[0];
}

// ---------------------------------------------------------------------------
extern "C" void kernel_launch(void* const* d_in, const int* in_sizes, int n_in,
                              void* d_out, int out_size, void* d_ws, size_t ws_size,
                              hipStream_t stream)
{
  (void)in_sizes; (void)n_in; (void)out_size; (void)ws_size;

  const float* x        = (const float*)d_in[0];
  const float* edge_attr= (const float*)d_in[1];
  const int*   eidx     = (const int*)d_in[2];
  const int*   batch    = (const int*)d_in[3];
  const float* linW     = (const float*)d_in[4];
  const float* linB     = (const float*)d_in[5];
  const float* msgW1    = (const float*)d_in[6];
  const float* msgB1    = (const float*)d_in[7];
  const float* msgG1    = (const float*)d_in[8];
  const float* msgBe1   = (const float*)d_in[9];
  const float* msgW2    = (const float*)d_in[10];
  const float* msgB2    = (const float*)d_in[11];
  const float* msgG2    = (const float*)d_in[12];
  const float* msgBe2   = (const float*)d_in[13];
  const float* updW1    = (const float*)d_in[14];
  const float* updB1    = (const float*)d_in[15];
  const float* updG1    = (const float*)d_in[16];
  const float* updBe1   = (const float*)d_in[17];
  const float* updW2    = (const float*)d_in[18];
  const float* updB2    = (const float*)d_in[19];
  const float* updG2    = (const float*)d_in[20];
  const float* updBe2   = (const float*)d_in[21];
  const float* predW    = (const float*)d_in[22];
  const float* predB    = (const float*)d_in[23];

  const int* srcI = eidx;        // edge_index[0] = source
  const int* dstI = eidx + NE;   // edge_index[1] = target

  char* p = (char*)d_ws;
  float* h  = (float*)p;            p += (size_t)NN * 64 * 4;
  unsigned short* t1 = (unsigned short*)p; p += (size_t)NE * 64 * 2;
  unsigned short* aggr = (unsigned short*)p; p += (size_t)NN * 64 * 2;
  unsigned short* u1 = (unsigned short*)p;   p += (size_t)NN * 64 * 2;
  unsigned short* Hd = (unsigned short*)p;   p += (size_t)NN * 64 * 2;
  unsigned short* Hs = (unsigned short*)p;   p += (size_t)NN * 64 * 2;
  float* stats = (float*)p;         p += 16 * STB * 4;
  float* sums = (float*)p;          p += NG * 64 * 4;
  int* deg = (int*)p;               p += (size_t)NN * 4;
  int* cursor = (int*)p;            p += (size_t)NN * 4;
  int* rowptr = (int*)p;            p += (size_t)(NN + 1) * 4;
  int* srcP = (int*)p;              p += (size_t)NE * 4;
  int* dstP = (int*)p;              p += (size_t)NE * 4;
  float* eaP = (float*)p;           p += (size_t)NE * 4 * 4;
  int* blockSums = (int*)p;         p += 256 * 4;
  int* blockOffs = (int*)p;         p += 256 * 4;

  hipMemsetAsync(stats, 0, (16 * STB + NG * 64) * sizeof(float), stream);
  hipMemsetAsync(deg, 0, NN * sizeof(int), stream);

  hist_kernel<<<(NE + 255) / 256, 256, 0, stream>>>(dstI, deg);
  scan_pass1<<<SCAN_BLOCKS, 256, 0, stream>>>(deg, blockSums);
  scan_pass2<<<1, 256, 0, stream>>>(blockSums, blockOffs);
  scan_pass3<<<SCAN_BLOCKS, 256, 0, stream>>>(deg, blockOffs, rowptr, cursor);
  fill_permute_kernel<<<(NE + 255) / 256, 256, 0, stream>>>(
      srcI, dstI, edge_attr, cursor, srcP, dstP, eaP);

  lin_in_kernel<<<(NN * 64 + 255) / 256, 256, 0, stream>>>(x, linW, linB, h);

  const float invE = 1.0f / (float)NE;
  const float invN = 1.0f / (float)NN;
  const int NB128 = (NN + 127) / 128;         // 391
  const int NB256 = (NN + 255) / 256;         // 196
  const int EB256 = (NE + 255) / 256;         // 1563

  for (int l = 0; l < 4; ++l) {
    float* st0 = stats + (l * 4 + 0) * STB;
    float* st1 = stats + (l * 4 + 1) * STB;
    float* st2 = stats + (l * 4 + 2) * STB;
    float* st3 = stats + (l * 4 + 3) * STB;
    const float* W1 = msgW1 + (size_t)l * 132 * 64;

    // Hd = h @ W1[0:64], Hs = h @ W1[64:128]  (bf16 out, MFMA)
    gemm_dual_mfma<<<NB128, 256, 0, stream>>>(h, W1, Hd, Hs);

    // t1[p] = Hd[dstP] + Hs[srcP] + eaP@W1[128:132] + b1 (bf16) ; stats(st0)
    edge_combine<<<2048, 256, 0, stream>>>(
        Hd, Hs, eaP, srcP, dstP, W1 + 128 * 64, msgB1 + l * 64,
        t1, st0);

    // t1 = relu(bn(t1)) @ msgW2 + b2 (bf16, in-place, MFMA) ; stats(st1)
    gemm64_bn_mfma<<<EB256, 256, 0, stream>>>(
        t1, msgW2 + (size_t)l * 64 * 64, msgB2 + l * 64,
        st0, msgG1 + l * 64, msgBe1 + l * 64, invE,
        t1, st1, NE);

    // aggr[n] = sum relu(bn(t2)) over CSR rows (wide sequential stream)
    aggregate_kernel<<<(NN * 64 + 255) / 256, 256, 0, stream>>>(
        t1, rowptr, st1, msgG2 + l * 64, msgBe2 + l * 64, invE, aggr);

    // u1 = [h|aggr] @ updW1 + b1 (MFMA, bf16 out) ; stats(st2)
    gemm_concat_mfma<<<NB128, 256, 0, stream>>>(
        h, aggr, updW1 + (size_t)l * 128 * 64, updB1 + l * 64,
        u1, st2, NN);

    // u1 = relu(bn(u1)) @ updW2 + b2 (bf16, in-place, MFMA) ; stats(st3)
    gemm64_bn_mfma<<<NB256, 256, 0, stream>>>(
        u1, updW2 + (size_t)l * 64 * 64, updB2 + l * 64,
        st2, updG1 + l * 64, updBe1 + l * 64, invN,
        u1, st3, NN);

    // h += relu(bn(u1))
    residual_kernel<<<(NN * 16 + 255) / 256, 256, 0, stream>>>(
        u1, st3, updG2 + l * 64, updBe2 + l * 64, invN, h);
  }

  pool_partial<<<(NN + POOL_NPB - 1) / POOL_NPB, 256, 0, stream>>>(h, batch, sums);
  pool_final<<<NG, 64, 0, stream>>>(sums, batch, predW, predB, (float*)d_out);
}

// Round 12
// 661.322 us; speedup vs baseline: 1.4862x; 1.0333x over previous
//
#include <hip/hip_runtime.h>

#define DEV __device__ __forceinline__

constexpr int NN = 50000;   // nodes
constexpr int NE = 400000;  // edges
constexpr int NG = 32;      // graphs
constexpr float EPSV = 1e-5f;
constexpr int SCAN_BLOCKS = 196;  // 196*256 = 50176 >= NN
constexpr int NSHARD = 8;         // stats shards (atomic-contention relief)
constexpr int STB = NSHARD * 128; // floats per BN-stats instance

typedef __attribute__((ext_vector_type(8))) short s16x8;
typedef __attribute__((ext_vector_type(4))) float f32x4;

DEV unsigned short f2b(float f) {  // fp32 -> bf16 RNE (finite inputs)
  union { float f; unsigned u; } x; x.f = f;
  unsigned r = x.u + 0x7fffu + ((x.u >> 16) & 1u);
  return (unsigned short)(r >> 16);
}
DEV float b2f(unsigned short u) {
  union { unsigned u; float f; } x; x.u = ((unsigned)u) << 16; return x.f;
}

DEV s16x8 frag_from_f32(const float* p) {
  const float4 v0 = *(const float4*)p;
  const float4 v1 = *(const float4*)(p + 4);
  s16x8 af;
  af[0] = (short)f2b(v0.x); af[1] = (short)f2b(v0.y);
  af[2] = (short)f2b(v0.z); af[3] = (short)f2b(v0.w);
  af[4] = (short)f2b(v1.x); af[5] = (short)f2b(v1.y);
  af[6] = (short)f2b(v1.z); af[7] = (short)f2b(v1.w);
  return af;
}

// sum the NSHARD shards of a stats instance and produce scale/shift for ch c.
// Call once per BLOCK (tid<64) and stage in LDS — never per thread.
DEV void bn_coeff(const float* __restrict__ st, const float* __restrict__ g,
                  const float* __restrict__ be, float invM, int c,
                  float& sc, float& sh) {
  float s = 0.f, s2 = 0.f;
#pragma unroll
  for (int k = 0; k < NSHARD; ++k) {
    s += st[k * 128 + c];
    s2 += st[k * 128 + 64 + c];
  }
  float mean = s * invM;
  float var = s2 * invM - mean * mean;
  sc = g[c] * rsqrtf(var + EPSV);
  sh = be[c] - mean * sc;
}

// ---------------------------------------------------------------------------
// lin_in: h = x @ W(11x64) + b
// ---------------------------------------------------------------------------
__global__ __launch_bounds__(256) void lin_in_kernel(
    const float* __restrict__ x, const float* __restrict__ W,
    const float* __restrict__ b, float* __restrict__ h)
{
  int gid = blockIdx.x * 256 + threadIdx.x;
  if (gid >= NN * 64) return;
  int n = gid >> 6, c = gid & 63;
  float acc = b[c];
#pragma unroll
  for (int k = 0; k < 11; ++k)
    acc = fmaf(x[n * 11 + k], W[k * 64 + c], acc);
  h[gid] = acc;
}

// ---------------------------------------------------------------------------
// CSR build: histogram -> hierarchical scan -> eid scatter -> seq permute
// ---------------------------------------------------------------------------
__global__ __launch_bounds__(256) void hist_kernel(
    const int* __restrict__ dstI, int* __restrict__ deg)
{
  int e = blockIdx.x * 256 + threadIdx.x;
  if (e < NE) atomicAdd(&deg[dstI[e]], 1);
}

__global__ __launch_bounds__(256) void scan_pass1(
    const int* __restrict__ deg, int* __restrict__ blockSums)
{
  __shared__ int red[4];
  int tid = threadIdx.x;
  int idx = blockIdx.x * 256 + tid;
  int v = (idx < NN) ? deg[idx] : 0;
#pragma unroll
  for (int off = 32; off > 0; off >>= 1) v += __shfl_down(v, off, 64);
  if ((tid & 63) == 0) red[tid >> 6] = v;
  __syncthreads();
  if (tid == 0) blockSums[blockIdx.x] = red[0] + red[1] + red[2] + red[3];
}

__global__ __launch_bounds__(256) void scan_pass2(
    const int* __restrict__ blockSums, int* __restrict__ blockOffs)
{
  __shared__ int part[256];
  int tid = threadIdx.x;
  int v = (tid < SCAN_BLOCKS) ? blockSums[tid] : 0;
  part[tid] = v;
  __syncthreads();
  for (int off = 1; off < 256; off <<= 1) {
    int t = 0;
    if (tid >= off) t = part[tid - off];
    __syncthreads();
    if (tid >= off) part[tid] += t;
    __syncthreads();
  }
  blockOffs[tid] = (tid == 0) ? 0 : part[tid - 1];
}

__global__ __launch_bounds__(256) void scan_pass3(
    const int* __restrict__ deg, const int* __restrict__ blockOffs,
    int* __restrict__ rowptr, int* __restrict__ cursor)
{
  __shared__ int part[256];
  int tid = threadIdx.x;
  int idx = blockIdx.x * 256 + tid;
  int v = (idx < NN) ? deg[idx] : 0;
  part[tid] = v;
  __syncthreads();
  for (int off = 1; off < 256; off <<= 1) {
    int t = 0;
    if (tid >= off) t = part[tid - off];
    __syncthreads();
    if (tid >= off) part[tid] += t;
    __syncthreads();
  }
  int excl = (tid == 0) ? 0 : part[tid - 1];
  int val = blockOffs[blockIdx.x] + excl;
  if (idx < NN) { rowptr[idx] = val; cursor[idx] = val; }
  if (idx == 0) rowptr[NN] = NE;
}

// phase A: scatter only 4B eid (minimal write-allocate traffic)
__global__ __launch_bounds__(256) void fill_pos_kernel(
    const int* __restrict__ dstI, int* __restrict__ cursor,
    int* __restrict__ eid)
{
  int e = blockIdx.x * 256 + threadIdx.x;
  if (e < NE) {
    int pos = atomicAdd(&cursor[dstI[e]], 1);
    eid[pos] = e;
  }
}

// phase B: sequential writes of srcP/dstP/eaP (gathered reads, no RMW lines)
__global__ __launch_bounds__(256) void permute_kernel(
    const int* __restrict__ eid, const int* __restrict__ srcI,
    const int* __restrict__ dstI, const float* __restrict__ ea,
    int* __restrict__ srcP, int* __restrict__ dstP,
    float* __restrict__ eaP)
{
  int p = blockIdx.x * 256 + threadIdx.x;
  if (p < NE) {
    int e = eid[p];
    srcP[p] = srcI[e];
    dstP[p] = dstI[e];
    *(float4*)&eaP[(size_t)p * 4] = *(const float4*)&ea[(size_t)e * 4];
  }
}

// ---------------------------------------------------------------------------
// gemm_dual_mfma: Hd = h @ W[0:64], Hs = h @ W[64:128] (bf16 out, MFMA)
// ---------------------------------------------------------------------------
__global__ __launch_bounds__(256) void gemm_dual_mfma(
    const float* __restrict__ h, const float* __restrict__ W, // 132x64
    unsigned short* __restrict__ Hd, unsigned short* __restrict__ Hs)
{
  __shared__ __align__(16) unsigned short Wt_s[2 * 64 * 72];  // [half][n][k]

  const int tid = threadIdx.x;
  const int lane = tid & 63;
  const int wave = tid >> 6;
  const int nn = lane & 15;
  const int kq = lane >> 4;

#pragma unroll
  for (int i = 0; i < 32; ++i) {
    int idx = i * 256 + tid;          // 8192 = 2*64*64
    int half = idx >> 12;
    int rem = idx & 4095;
    int k = rem >> 6, n = rem & 63;
    Wt_s[half * 4608 + n * 72 + k] = f2b(W[idx]);
  }
  __syncthreads();

  s16x8 bfrag[2][4][2];  // [out][nt][kc]
#pragma unroll
  for (int o = 0; o < 2; ++o)
#pragma unroll
    for (int nt = 0; nt < 4; ++nt)
#pragma unroll
      for (int kc = 0; kc < 2; ++kc) {
        const unsigned short* p =
            &Wt_s[o * 4608 + (nt * 16 + nn) * 72 + kc * 32 + kq * 8];
#pragma unroll
        for (int j = 0; j < 8; ++j) bfrag[o][nt][kc][j] = (short)p[j];
      }

  const int rbase = blockIdx.x * 128 + wave * 32;

  f32x4 acc[2][2][4];  // [out][rt][nt]
#pragma unroll
  for (int o = 0; o < 2; ++o)
#pragma unroll
    for (int rt = 0; rt < 2; ++rt)
#pragma unroll
      for (int nt = 0; nt < 4; ++nt) acc[o][rt][nt] = (f32x4){0.f, 0.f, 0.f, 0.f};

#pragma unroll
  for (int rt = 0; rt < 2; ++rt) {
    int row = rbase + rt * 16 + nn;
    int rowc = row < NN ? row : NN - 1;
#pragma unroll
    for (int kc = 0; kc < 2; ++kc) {
      s16x8 af = frag_from_f32(&h[(size_t)rowc * 64 + kc * 32 + kq * 8]);
#pragma unroll
      for (int o = 0; o < 2; ++o)
#pragma unroll
        for (int nt = 0; nt < 4; ++nt)
          acc[o][rt][nt] = __builtin_amdgcn_mfma_f32_16x16x32_bf16(
              af, bfrag[o][nt][kc], acc[o][rt][nt], 0, 0, 0);
    }
  }

#pragma unroll
  for (int rt = 0; rt < 2; ++rt)
#pragma unroll
    for (int nt = 0; nt < 4; ++nt) {
      int col = nt * 16 + nn;
#pragma unroll
      for (int reg = 0; reg < 4; ++reg) {
        int row = rbase + rt * 16 + kq * 4 + reg;
        if (row < NN) {
          Hd[(size_t)row * 64 + col] = f2b(acc[0][rt][nt][reg]);
          Hs[(size_t)row * 64 + col] = f2b(acc[1][rt][nt][reg]);
        }
      }
    }
}

// ---------------------------------------------------------------------------
// edge_combine: t1[p] = Hd[dstP[p]] + Hs[srcP[p]] + eaP[p]@Wb + b (bf16 out)
// 8 lanes/edge, 16B ops, 4x grid-stride unroll (all loads up front).
// ---------------------------------------------------------------------------
__global__ __launch_bounds__(256) void edge_combine(
    const unsigned short* __restrict__ Hd, const unsigned short* __restrict__ Hs,
    const float* __restrict__ eaP, const int* __restrict__ srcP,
    const int* __restrict__ dstP, const float* __restrict__ Wb, // 4x64
    const float* __restrict__ bias, unsigned short* __restrict__ t1,
    float* __restrict__ outStats)
{
  __shared__ float red_s[128];
  const int tid = threadIdx.x;
  const int c0 = (tid & 7) * 8;
  float bv[8], w0[8], w1[8], w2[8], w3[8];
#pragma unroll
  for (int j = 0; j < 8; ++j) {
    bv[j] = bias[c0 + j];
    w0[j] = Wb[0 * 64 + c0 + j];
    w1[j] = Wb[1 * 64 + c0 + j];
    w2[j] = Wb[2 * 64 + c0 + j];
    w3[j] = Wb[3 * 64 + c0 + j];
  }

  float s[8], s2[8];
#pragma unroll
  for (int j = 0; j < 8; ++j) { s[j] = 0.f; s2[j] = 0.f; }

  const int e0 = (blockIdx.x * 256 + tid) >> 3;
  const int estep = (gridDim.x * 256) >> 3;

  for (int e = e0; e < NE; e += 4 * estep) {
    bool has[4];
    uint4 hd[4], hs[4];
    float4 av[4];
    int eidx4[4];
#pragma unroll
    for (int u = 0; u < 4; ++u) {
      int ee = e + u * estep;
      has[u] = ee < NE;
      int ec = has[u] ? ee : e;
      eidx4[u] = ec;
      int si = srcP[ec], di = dstP[ec];
      av[u] = *(const float4*)&eaP[(size_t)ec * 4];
      hd[u] = *(const uint4*)&Hd[(size_t)di * 64 + c0];
      hs[u] = *(const uint4*)&Hs[(size_t)si * 64 + c0];
    }
#pragma unroll
    for (int u = 0; u < 4; ++u) {
      if (!has[u]) continue;
      const unsigned hdw[4] = {hd[u].x, hd[u].y, hd[u].z, hd[u].w};
      const unsigned hsw[4] = {hs[u].x, hs[u].y, hs[u].z, hs[u].w};
      unsigned short ob[8];
#pragma unroll
      for (int d = 0; d < 4; ++d) {
        union { unsigned uu; float f; } a0, a1, b0, b1u;
        a0.uu = (hdw[d] & 0xffffu) << 16; a1.uu = hdw[d] & 0xffff0000u;
        b0.uu = (hsw[d] & 0xffffu) << 16; b1u.uu = hsw[d] & 0xffff0000u;
        int j0 = d * 2, j1 = d * 2 + 1;
        float y0 = a0.f + b0.f + bv[j0] + av[u].x * w0[j0] + av[u].y * w1[j0] + av[u].z * w2[j0] + av[u].w * w3[j0];
        float y1 = a1.f + b1u.f + bv[j1] + av[u].x * w0[j1] + av[u].y * w1[j1] + av[u].z * w2[j1] + av[u].w * w3[j1];
        ob[j0] = f2b(y0); ob[j1] = f2b(y1);
        s[j0] += y0; s2[j0] += y0 * y0;
        s[j1] += y1; s2[j1] += y1 * y1;
      }
      *(uint4*)&t1[(size_t)eidx4[u] * 64 + c0] = *(const uint4*)ob;
    }
  }
#pragma unroll
  for (int j = 0; j < 8; ++j) {
    s[j] += __shfl_xor(s[j], 8, 64);
    s[j] += __shfl_xor(s[j], 16, 64);
    s[j] += __shfl_xor(s[j], 32, 64);
    s2[j] += __shfl_xor(s2[j], 8, 64);
    s2[j] += __shfl_xor(s2[j], 16, 64);
    s2[j] += __shfl_xor(s2[j], 32, 64);
  }
  if (tid < 128) red_s[tid] = 0.f;
  __syncthreads();
  if ((tid & 63) < 8) {
#pragma unroll
    for (int j = 0; j < 8; ++j) {
      atomicAdd(&red_s[c0 + j], s[j]);
      atomicAdd(&red_s[64 + c0 + j], s2[j]);
    }
  }
  __syncthreads();
  if (tid < 128)
    atomicAdd(&outStats[(blockIdx.x & (NSHARD - 1)) * 128 + tid], red_s[tid]);
}

// ---------------------------------------------------------------------------
// gemm64_bn_mfma: out = relu(bn(A)) @ W + b — bf16 in/out, MFMA, in-place ok.
// 512-row block, 2 chunks of 64 rows per wave. Chunk-1 loads issued before
// chunk-0 epilogue (latency hidden); W-staging + stats atomics amortized 2x.
// In-place safe: each wave reads only its own rows (clamped OOB reads may
// see other waves' already-written rows; those results are discarded).
// ---------------------------------------------------------------------------
__global__ __launch_bounds__(256) void gemm64_bn_mfma(
    const unsigned short* A0,         // bf16 M x 64 (may alias outp)
    const float* __restrict__ W,      // 64 x 64 fp32
    const float* __restrict__ bias,
    const float* __restrict__ inStats,
    const float* __restrict__ inG,
    const float* __restrict__ inBe,
    float invM_in,
    unsigned short* outp,             // bf16 M x 64
    float* __restrict__ outStats,
    int M)
{
  __shared__ __align__(16) unsigned short Wt_s[64 * 72];
  __shared__ float scale_s[64];
  __shared__ float shift_s[64];
  __shared__ float red_s[128];

  const int tid = threadIdx.x;
  const int lane = tid & 63;
  const int wave = tid >> 6;
  const int nn = lane & 15;
  const int kq = lane >> 4;

  if (tid < 64) {
    float sc, sh;
    bn_coeff(inStats, inG, inBe, invM_in, tid, sc, sh);
    scale_s[tid] = sc;
    shift_s[tid] = sh;
  }
#pragma unroll
  for (int i = 0; i < 16; ++i) {
    int idx = i * 256 + tid;
    int k = idx >> 6, n = idx & 63;
    Wt_s[n * 72 + k] = f2b(W[idx]);
  }
  __syncthreads();

  s16x8 bfrag[4][2];
#pragma unroll
  for (int nt = 0; nt < 4; ++nt)
#pragma unroll
    for (int kc = 0; kc < 2; ++kc)
      bfrag[nt][kc] = *(const s16x8*)&Wt_s[(nt * 16 + nn) * 72 + kc * 32 + kq * 8];

  float scf[2][8], shf[2][8];
#pragma unroll
  for (int kc = 0; kc < 2; ++kc) {
    int k0 = kc * 32 + kq * 8;
    float4 a = *(const float4*)&scale_s[k0];
    float4 b = *(const float4*)&scale_s[k0 + 4];
    float4 c = *(const float4*)&shift_s[k0];
    float4 d = *(const float4*)&shift_s[k0 + 4];
    scf[kc][0] = a.x; scf[kc][1] = a.y; scf[kc][2] = a.z; scf[kc][3] = a.w;
    scf[kc][4] = b.x; scf[kc][5] = b.y; scf[kc][6] = b.z; scf[kc][7] = b.w;
    shf[kc][0] = c.x; shf[kc][1] = c.y; shf[kc][2] = c.z; shf[kc][3] = c.w;
    shf[kc][4] = d.x; shf[kc][5] = d.y; shf[kc][6] = d.z; shf[kc][7] = d.w;
  }

  float bcol[4];
#pragma unroll
  for (int nt = 0; nt < 4; ++nt) bcol[nt] = bias[nt * 16 + nn];

  float s[4] = {0.f, 0.f, 0.f, 0.f};
  float s2[4] = {0.f, 0.f, 0.f, 0.f};

  uint4 raw[4][2];
  f32x4 acc[4][4];

  // ---- chunk 0 loads ----
  const int rb0 = blockIdx.x * 512 + wave * 64;
#pragma unroll
  for (int rt = 0; rt < 4; ++rt) {
    int row = rb0 + rt * 16 + nn;
    int rowc = row < M ? row : M - 1;
#pragma unroll
    for (int kc = 0; kc < 2; ++kc)
      raw[rt][kc] = *(const uint4*)&A0[(size_t)rowc * 64 + kc * 32 + kq * 8];
  }

  // ---- chunk 0 compute ----
#pragma unroll
  for (int rt = 0; rt < 4; ++rt)
#pragma unroll
    for (int nt = 0; nt < 4; ++nt) acc[rt][nt] = (f32x4){0.f, 0.f, 0.f, 0.f};
#pragma unroll
  for (int rt = 0; rt < 4; ++rt) {
#pragma unroll
    for (int kc = 0; kc < 2; ++kc) {
      unsigned wbits[4] = {raw[rt][kc].x, raw[rt][kc].y, raw[rt][kc].z, raw[rt][kc].w};
      s16x8 af;
#pragma unroll
      for (int d = 0; d < 4; ++d) {
        union { unsigned u; float f; } lo, hi;
        lo.u = (wbits[d] & 0xffffu) << 16;
        hi.u = wbits[d] & 0xffff0000u;
        int j0 = d * 2, j1 = d * 2 + 1;
        af[j0] = (short)f2b(fmaxf(fmaf(scf[kc][j0], lo.f, shf[kc][j0]), 0.f));
        af[j1] = (short)f2b(fmaxf(fmaf(scf[kc][j1], hi.f, shf[kc][j1]), 0.f));
      }
#pragma unroll
      for (int nt = 0; nt < 4; ++nt)
        acc[rt][nt] = __builtin_amdgcn_mfma_f32_16x16x32_bf16(
            af, bfrag[nt][kc], acc[rt][nt], 0, 0, 0);
    }
  }

  // ---- chunk 1 loads (overlap with chunk 0 epilogue) ----
  const int rb1 = rb0 + 256;
#pragma unroll
  for (int rt = 0; rt < 4; ++rt) {
    int row = rb1 + rt * 16 + nn;
    int rowc = row < M ? row : M - 1;
#pragma unroll
    for (int kc = 0; kc < 2; ++kc)
      raw[rt][kc] = *(const uint4*)&A0[(size_t)rowc * 64 + kc * 32 + kq * 8];
  }

  // ---- chunk 0 epilogue ----
#pragma unroll
  for (int rt = 0; rt < 4; ++rt)
#pragma unroll
    for (int nt = 0; nt < 4; ++nt) {
      int col = nt * 16 + nn;
#pragma unroll
      for (int reg = 0; reg < 4; ++reg) {
        int row = rb0 + rt * 16 + kq * 4 + reg;
        if (row < M) {
          float y = acc[rt][nt][reg] + bcol[nt];
          outp[(size_t)row * 64 + col] = f2b(y);
          s[nt] += y; s2[nt] += y * y;
        }
      }
    }

  // ---- chunk 1 compute ----
#pragma unroll
  for (int rt = 0; rt < 4; ++rt)
#pragma unroll
    for (int nt = 0; nt < 4; ++nt) acc[rt][nt] = (f32x4){0.f, 0.f, 0.f, 0.f};
#pragma unroll
  for (int rt = 0; rt < 4; ++rt) {
#pragma unroll
    for (int kc = 0; kc < 2; ++kc) {
      unsigned wbits[4] = {raw[rt][kc].x, raw[rt][kc].y, raw[rt][kc].z, raw[rt][kc].w};
      s16x8 af;
#pragma unroll
      for (int d = 0; d < 4; ++d) {
        union { unsigned u; float f; } lo, hi;
        lo.u = (wbits[d] & 0xffffu) << 16;
        hi.u = wbits[d] & 0xffff0000u;
        int j0 = d * 2, j1 = d * 2 + 1;
        af[j0] = (short)f2b(fmaxf(fmaf(scf[kc][j0], lo.f, shf[kc][j0]), 0.f));
        af[j1] = (short)f2b(fmaxf(fmaf(scf[kc][j1], hi.f, shf[kc][j1]), 0.f));
      }
#pragma unroll
      for (int nt = 0; nt < 4; ++nt)
        acc[rt][nt] = __builtin_amdgcn_mfma_f32_16x16x32_bf16(
            af, bfrag[nt][kc], acc[rt][nt], 0, 0, 0);
    }
  }

  // ---- chunk 1 epilogue ----
#pragma unroll
  for (int rt = 0; rt < 4; ++rt)
#pragma unroll
    for (int nt = 0; nt < 4; ++nt) {
      int col = nt * 16 + nn;
#pragma unroll
      for (int reg = 0; reg < 4; ++reg) {
        int row = rb1 + rt * 16 + kq * 4 + reg;
        if (row < M) {
          float y = acc[rt][nt][reg] + bcol[nt];
          outp[(size_t)row * 64 + col] = f2b(y);
          s[nt] += y; s2[nt] += y * y;
        }
      }
    }

  // ---- stats reduction (once per block) ----
#pragma unroll
  for (int nt = 0; nt < 4; ++nt) {
    s[nt] += __shfl_xor(s[nt], 16, 64);
    s[nt] += __shfl_xor(s[nt], 32, 64);
    s2[nt] += __shfl_xor(s2[nt], 16, 64);
    s2[nt] += __shfl_xor(s2[nt], 32, 64);
  }
  if (tid < 128) red_s[tid] = 0.f;
  __syncthreads();
  if (lane < 16) {
#pragma unroll
    for (int nt = 0; nt < 4; ++nt) {
      atomicAdd(&red_s[nt * 16 + nn], s[nt]);
      atomicAdd(&red_s[64 + nt * 16 + nn], s2[nt]);
    }
  }
  __syncthreads();
  if (tid < 128)
    atomicAdd(&outStats[(blockIdx.x & (NSHARD - 1)) * 128 + tid], red_s[tid]);
}

// ---------------------------------------------------------------------------
// gemm_concat_mfma: u1 = [h(fp32)|aggr(bf16)] @ W(128x64) + b (bf16 out)
// ---------------------------------------------------------------------------
__global__ __launch_bounds__(256) void gemm_concat_mfma(
    const float* __restrict__ A0,            // h fp32
    const unsigned short* __restrict__ A1b,  // aggr bf16
    const float* __restrict__ W,             // 128 x 64
    const float* __restrict__ bias,
    unsigned short* __restrict__ outp,       // u1 bf16
    float* __restrict__ outStats,
    int M)
{
  __shared__ __align__(16) unsigned short Wt_s[64 * 136];
  __shared__ float red_s[128];

  const int tid = threadIdx.x;
  const int lane = tid & 63;
  const int wave = tid >> 6;
  const int nn = lane & 15;
  const int kq = lane >> 4;

#pragma unroll
  for (int i = 0; i < 32; ++i) {
    int idx = i * 256 + tid;          // 8192
    int k = idx >> 6, n = idx & 63;
    Wt_s[n * 136 + k] = f2b(W[idx]);
  }
  __syncthreads();

  s16x8 bfrag[4][4];  // [nt][kc]
#pragma unroll
  for (int nt = 0; nt < 4; ++nt)
#pragma unroll
    for (int kc = 0; kc < 4; ++kc) {
      const unsigned short* p = &Wt_s[(nt * 16 + nn) * 136 + kc * 32 + kq * 8];
#pragma unroll
      for (int j = 0; j < 8; ++j) bfrag[nt][kc][j] = (short)p[j];
    }

  const int rbase = blockIdx.x * 128 + wave * 32;

  f32x4 acc[2][4];
#pragma unroll
  for (int rt = 0; rt < 2; ++rt)
#pragma unroll
    for (int nt = 0; nt < 4; ++nt) acc[rt][nt] = (f32x4){0.f, 0.f, 0.f, 0.f};

#pragma unroll
  for (int rt = 0; rt < 2; ++rt) {
    int row = rbase + rt * 16 + nn;
    int rowc = row < M ? row : M - 1;
#pragma unroll
    for (int kc = 0; kc < 4; ++kc) {
      s16x8 af;
      if (kc < 2) {
        af = frag_from_f32(&A0[(size_t)rowc * 64 + kc * 32 + kq * 8]);
      } else {
        af = *(const s16x8*)&A1b[(size_t)rowc * 64 + (kc - 2) * 32 + kq * 8];
      }
#pragma unroll
      for (int nt = 0; nt < 4; ++nt)
        acc[rt][nt] = __builtin_amdgcn_mfma_f32_16x16x32_bf16(
            af, bfrag[nt][kc], acc[rt][nt], 0, 0, 0);
    }
  }

  float bcol[4];
#pragma unroll
  for (int nt = 0; nt < 4; ++nt) bcol[nt] = bias[nt * 16 + nn];

  float s[4] = {0.f, 0.f, 0.f, 0.f};
  float s2[4] = {0.f, 0.f, 0.f, 0.f};
#pragma unroll
  for (int rt = 0; rt < 2; ++rt)
#pragma unroll
    for (int nt = 0; nt < 4; ++nt) {
      int col = nt * 16 + nn;
#pragma unroll
      for (int reg = 0; reg < 4; ++reg) {
        int row = rbase + rt * 16 + kq * 4 + reg;
        if (row < M) {
          float y = acc[rt][nt][reg] + bcol[nt];
          outp[(size_t)row * 64 + col] = f2b(y);
          s[nt] += y; s2[nt] += y * y;
        }
      }
    }
#pragma unroll
  for (int nt = 0; nt < 4; ++nt) {
    s[nt] += __shfl_xor(s[nt], 16, 64);
    s[nt] += __shfl_xor(s[nt], 32, 64);
    s2[nt] += __shfl_xor(s2[nt], 16, 64);
    s2[nt] += __shfl_xor(s2[nt], 32, 64);
  }
  if (tid < 128) red_s[tid] = 0.f;
  __syncthreads();
  if (lane < 16) {
#pragma unroll
    for (int nt = 0; nt < 4; ++nt) {
      atomicAdd(&red_s[nt * 16 + nn], s[nt]);
      atomicAdd(&red_s[64 + nt * 16 + nn], s2[nt]);
    }
  }
  __syncthreads();
  if (tid < 128)
    atomicAdd(&outStats[(blockIdx.x & (NSHARD - 1)) * 128 + tid], red_s[tid]);
}

// ---------------------------------------------------------------------------
// aggregate (wide): lane = (8 channels)x(row-octet). uint4 loads: 16B/lane,
// a wave covers 8 full CSR rows per load, 16 rows per iteration.
// BN coeffs staged in LDS once per block. xor-shuffle(8,16,32) reduce.
// ---------------------------------------------------------------------------
__global__ __launch_bounds__(256) void aggregate_kernel(
    const unsigned short* __restrict__ t2, const int* __restrict__ rowptr,
    const float* __restrict__ stats, const float* __restrict__ g,
    const float* __restrict__ be, float invM,
    unsigned short* __restrict__ aggr)
{
  __shared__ float sc_s[64], sh_s[64];
  const int tid = threadIdx.x;
  if (tid < 64) {
    float sc, sh;
    bn_coeff(stats, g, be, invM, tid, sc, sh);
    sc_s[tid] = sc;
    sh_s[tid] = sh;
  }
  __syncthreads();

  int node = (blockIdx.x * 256 + tid) >> 6;
  int lane = tid & 63;
  if (node >= NN) return;
  const int c8 = (lane & 7) * 8;    // this lane's 8 channels
  const int rq = lane >> 3;         // row offset within octet (0..7)

  float sc[8], sh[8];
#pragma unroll
  for (int j = 0; j < 8; ++j) {
    sc[j] = sc_s[c8 + j];
    sh[j] = sh_s[c8 + j];
  }

  int lo = rowptr[node], hi = rowptr[node + 1];
  float acc[8] = {0.f, 0.f, 0.f, 0.f, 0.f, 0.f, 0.f, 0.f};

  for (int i = lo; i < hi; i += 16) {
    int r0 = i + rq;
    int r1 = i + 8 + rq;
    bool h0 = r0 < hi, h1 = r1 < hi;
    uint4 v0 = make_uint4(0u, 0u, 0u, 0u), v1 = make_uint4(0u, 0u, 0u, 0u);
    if (h0) v0 = *(const uint4*)&t2[(size_t)r0 * 64 + c8];
    if (h1) v1 = *(const uint4*)&t2[(size_t)r1 * 64 + c8];
    if (h0) {
      const unsigned w[4] = {v0.x, v0.y, v0.z, v0.w};
#pragma unroll
      for (int d = 0; d < 4; ++d) {
        union { unsigned u; float f; } a0, a1;
        a0.u = (w[d] & 0xffffu) << 16;
        a1.u = w[d] & 0xffff0000u;
        acc[d * 2] += fmaxf(fmaf(sc[d * 2], a0.f, sh[d * 2]), 0.f);
        acc[d * 2 + 1] += fmaxf(fmaf(sc[d * 2 + 1], a1.f, sh[d * 2 + 1]), 0.f);
      }
    }
    if (h1) {
      const unsigned w[4] = {v1.x, v1.y, v1.z, v1.w};
#pragma unroll
      for (int d = 0; d < 4; ++d) {
        union { unsigned u; float f; } a0, a1;
        a0.u = (w[d] & 0xffffu) << 16;
        a1.u = w[d] & 0xffff0000u;
        acc[d * 2] += fmaxf(fmaf(sc[d * 2], a0.f, sh[d * 2]), 0.f);
        acc[d * 2 + 1] += fmaxf(fmaf(sc[d * 2 + 1], a1.f, sh[d * 2 + 1]), 0.f);
      }
    }
  }
#pragma unroll
  for (int j = 0; j < 8; ++j) {
    acc[j] += __shfl_xor(acc[j], 8, 64);
    acc[j] += __shfl_xor(acc[j], 16, 64);
    acc[j] += __shfl_xor(acc[j], 32, 64);
  }
  if (rq == 0) {
    unsigned short o[8];
#pragma unroll
    for (int j = 0; j < 8; ++j) o[j] = f2b(acc[j]);
    *(uint4*)&aggr[(size_t)node * 64 + c8] = *(const uint4*)o;
  }
}

// ---------------------------------------------------------------------------
// residual: h += relu(bn(u2_bf16))   (BN coeffs staged in LDS per block)
// ---------------------------------------------------------------------------
__global__ __launch_bounds__(256) void residual_kernel(
    const unsigned short* __restrict__ u2, const float* __restrict__ stats,
    const float* __restrict__ g, const float* __restrict__ be,
    float invM, float* __restrict__ h)
{
  __shared__ float sc_s[64], sh_s[64];
  const int tid = threadIdx.x;
  if (tid < 64) {
    float sc, sh;
    bn_coeff(stats, g, be, invM, tid, sc, sh);
    sc_s[tid] = sc;
    sh_s[tid] = sh;
  }
  __syncthreads();

  int gid = blockIdx.x * 256 + tid;
  if (gid >= NN * 16) return;
  int c = (gid & 15) * 4;
  ushort4 v4 = *(const ushort4*)&u2[(size_t)gid * 4];
  float4 hv = *(const float4*)&h[(size_t)gid * 4];
  const unsigned short vu[4] = {v4.x, v4.y, v4.z, v4.w};
  float* hp = (float*)&hv;
#pragma unroll
  for (int j = 0; j < 4; ++j)
    hp[j] += fmaxf(fmaf(sc_s[c + j], b2f(vu[j]), sh_s[c + j]), 0.f);
  *(float4*)&h[(size_t)gid * 4] = hv;
}

// ---------------------------------------------------------------------------
// pool: partial per-graph column sums, then tiny final with prediction head
// ---------------------------------------------------------------------------
constexpr int POOL_NPB = 128;  // nodes per block

__global__ __launch_bounds__(256) void pool_partial(
    const float* __restrict__ h, const int* __restrict__ batch,
    float* __restrict__ sums)  // NG x 64
{
  int lane = threadIdx.x & 63;
  int wave = threadIdx.x >> 6;
  int base = blockIdx.x * POOL_NPB;
  float acc = 0.f;
  int gcur = -1;
  for (int i = wave; i < POOL_NPB; i += 4) {
    int n = base + i;
    if (n >= NN) break;
    int g = batch[n];
    if (g != gcur) {
      if (gcur >= 0) atomicAdd(&sums[gcur * 64 + lane], acc);
      gcur = g;
      acc = 0.f;
    }
    acc += h[(size_t)n * 64 + lane];
  }
  if (gcur >= 0) atomicAdd(&sums[gcur * 64 + lane], acc);
}

DEV int lower_bound_i(const int* __restrict__ a, int n, int v) {
  int lo = 0, hi = n;
  while (lo < hi) {
    int m = (lo + hi) >> 1;
    if (a[m] < v) lo = m + 1; else hi = m;
  }
  return lo;
}

__global__ __launch_bounds__(64) void pool_final(
    const float* __restrict__ sums, const int* __restrict__ batch,
    const float* __restrict__ predW, const float* __restrict__ predB,
    float* __restrict__ out)
{
  int g = blockIdx.x;
  int lane = threadIdx.x;
  int lo = lower_bound_i(batch, NN, g);
  int hi = lower_bound_i(batch, NN, g + 1);
  float cnt = fmaxf((float)(hi - lo), 1.0f);
  float p = sums[g * 64 + lane] / cnt * predW[lane];
#pragma unroll
  for (int off = 32; off > 0; off >>= 1) p += __shfl_down(p, off, 64);
  if (lane == 0) out[g] = p + predB[0];
}

// ---------------------------------------------------------------------------
extern "C" void kernel_launch(void* const* d_in, const int* in_sizes, int n_in,
                              void* d_out, int out_size, void* d_ws, size_t ws_size,
                              hipStream_t stream)
{
  (void)in_sizes; (void)n_in; (void)out_size; (void)ws_size;

  const float* x        = (const float*)d_in[0];
  const float* edge_attr= (const float*)d_in[1];
  const int*   eidx     = (const int*)d_in[2];
  const int*   batch    = (const int*)d_in[3];
  const float* linW     = (const float*)d_in[4];
  const float* linB     = (const float*)d_in[5];
  const float* msgW1    = (const float*)d_in[6];
  const float* msgB1    = (const float*)d_in[7];
  const float* msgG1    = (const float*)d_in[8];
  const float* msgBe1   = (const float*)d_in[9];
  const float* msgW2    = (const float*)d_in[10];
  const float* msgB2    = (const float*)d_in[11];
  const float* msgG2    = (const float*)d_in[12];
  const float* msgBe2   = (const float*)d_in[13];
  const float* updW1    = (const float*)d_in[14];
  const float* updB1    = (const float*)d_in[15];
  const float* updG1    = (const float*)d_in[16];
  const float* updBe1   = (const float*)d_in[17];
  const float* updW2    = (const float*)d_in[18];
  const float* updB2    = (const float*)d_in[19];
  const float* updG2    = (const float*)d_in[20];
  const float* updBe2   = (const float*)d_in[21];
  const float* predW    = (const float*)d_in[22];
  const float* predB    = (const float*)d_in[23];

  const int* srcI = eidx;        // edge_index[0] = source
  const int* dstI = eidx + NE;   // edge_index[1] = target

  char* p = (char*)d_ws;
  float* h  = (float*)p;            p += (size_t)NN * 64 * 4;
  unsigned short* t1 = (unsigned short*)p; p += (size_t)NE * 64 * 2;
  unsigned short* aggr = (unsigned short*)p; p += (size_t)NN * 64 * 2;
  unsigned short* u1 = (unsigned short*)p;   p += (size_t)NN * 64 * 2;
  unsigned short* Hd = (unsigned short*)p;   p += (size_t)NN * 64 * 2;
  unsigned short* Hs = (unsigned short*)p;   p += (size_t)NN * 64 * 2;
  float* stats = (float*)p;         p += 16 * STB * 4;
  float* sums = (float*)p;          p += NG * 64 * 4;
  int* deg = (int*)p;               p += (size_t)NN * 4;
  int* cursor = (int*)p;            p += (size_t)NN * 4;
  int* rowptr = (int*)p;            p += (size_t)(NN + 1) * 4;
  int* eid = (int*)p;               p += (size_t)NE * 4;
  int* srcP = (int*)p;              p += (size_t)NE * 4;
  int* dstP = (int*)p;              p += (size_t)NE * 4;
  float* eaP = (float*)p;           p += (size_t)NE * 4 * 4;
  int* blockSums = (int*)p;         p += 256 * 4;
  int* blockOffs = (int*)p;         p += 256 * 4;

  hipMemsetAsync(stats, 0, (16 * STB + NG * 64) * sizeof(float), stream);
  hipMemsetAsync(deg, 0, NN * sizeof(int), stream);

  hist_kernel<<<(NE + 255) / 256, 256, 0, stream>>>(dstI, deg);
  scan_pass1<<<SCAN_BLOCKS, 256, 0, stream>>>(deg, blockSums);
  scan_pass2<<<1, 256, 0, stream>>>(blockSums, blockOffs);
  scan_pass3<<<SCAN_BLOCKS, 256, 0, stream>>>(deg, blockOffs, rowptr, cursor);
  fill_pos_kernel<<<(NE + 255) / 256, 256, 0, stream>>>(dstI, cursor, eid);
  permute_kernel<<<(NE + 255) / 256, 256, 0, stream>>>(
      eid, srcI, dstI, edge_attr, srcP, dstP, eaP);

  lin_in_kernel<<<(NN * 64 + 255) / 256, 256, 0, stream>>>(x, linW, linB, h);

  const float invE = 1.0f / (float)NE;
  const float invN = 1.0f / (float)NN;
  const int NB128 = (NN + 127) / 128;         // 391
  const int NB512 = (NN + 511) / 512;         // 98
  const int EB512 = (NE + 511) / 512;         // 782

  for (int l = 0; l < 4; ++l) {
    float* st0 = stats + (l * 4 + 0) * STB;
    float* st1 = stats + (l * 4 + 1) * STB;
    float* st2 = stats + (l * 4 + 2) * STB;
    float* st3 = stats + (l * 4 + 3) * STB;
    const float* W1 = msgW1 + (size_t)l * 132 * 64;

    // Hd = h @ W1[0:64], Hs = h @ W1[64:128]  (bf16 out, MFMA)
    gemm_dual_mfma<<<NB128, 256, 0, stream>>>(h, W1, Hd, Hs);

    // t1[p] = Hd[dstP] + Hs[srcP] + eaP@W1[128:132] + b1 (bf16) ; stats(st0)
    edge_combine<<<2048, 256, 0, stream>>>(
        Hd, Hs, eaP, srcP, dstP, W1 + 128 * 64, msgB1 + l * 64,
        t1, st0);

    // t1 = relu(bn(t1)) @ msgW2 + b2 (bf16, in-place, MFMA) ; stats(st1)
    gemm64_bn_mfma<<<EB512, 256, 0, stream>>>(
        t1, msgW2 + (size_t)l * 64 * 64, msgB2 + l * 64,
        st0, msgG1 + l * 64, msgBe1 + l * 64, invE,
        t1, st1, NE);

    // aggr[n] = sum relu(bn(t2)) over CSR rows (wide sequential stream)
    aggregate_kernel<<<(NN * 64 + 255) / 256, 256, 0, stream>>>(
        t1, rowptr, st1, msgG2 + l * 64, msgBe2 + l * 64, invE, aggr);

    // u1 = [h|aggr] @ updW1 + b1 (MFMA, bf16 out) ; stats(st2)
    gemm_concat_mfma<<<NB128, 256, 0, stream>>>(
        h, aggr, updW1 + (size_t)l * 128 * 64, updB1 + l * 64,
        u1, st2, NN);

    // u1 = relu(bn(u1)) @ updW2 + b2 (bf16, in-place, MFMA) ; stats(st3)
    gemm64_bn_mfma<<<NB512, 256, 0, stream>>>(
        u1, updW2 + (size_t)l * 64 * 64, updB2 + l * 64,
        st2, updG1 + l * 64, updBe1 + l * 64, invN,
        u1, st3, NN);

    // h += relu(bn(u1))
    residual_kernel<<<(NN * 16 + 255) / 256, 256, 0, stream>>>(
        u1, st3, updG2 + l * 64, updBe2 + l * 64, invN, h);
  }

  pool_partial<<<(NN + POOL_NPB - 1) / POOL_NPB, 256, 0, stream>>>(h, batch, sums);
  pool_final<<<NG, 64, 0, stream>>>(sums, batch, predW, predB, (float*)d_out);
}